// Round 1
// baseline (2752.864 us; speedup 1.0000x reference)
//
#include <hip/hip_runtime.h>

#define NN 50000
#define NE 800000
#define H 256

typedef __bf16 bf16x8 __attribute__((ext_vector_type(8)));
typedef float f32x4 __attribute__((ext_vector_type(4)));

static __device__ __forceinline__ f32x4 mfma16(bf16x8 a, bf16x8 b, f32x4 c) {
  return __builtin_amdgcn_mfma_f32_16x16x32_bf16(a, b, c, 0, 0, 0);
}
static __device__ __forceinline__ bf16x8 bzero8() {
  bf16x8 z;
#pragma unroll
  for (int j = 0; j < 8; ++j) z[j] = (__bf16)0.f;
  return z;
}
static __device__ __forceinline__ float silu_f(float v) {
  return v / (1.f + __expf(-v));
}

// ---------------------------------------------------------------------------
// Weight prep: fp32 -> bf16, K padded to mult of 32, layout [chunk][n][32k]
// so a B fragment (n fixed, 8 consecutive k) is one 16B contiguous load and a
// full wave covers a contiguous 1KB region.
// e1p: [3][18][256][32]  (K 560->576, zero pad)
// e2p: [3][ 8][256][32]
// n1p: [3][17][256][32]  (K 528->544, zero pad)
// n2p: [3][ 8][256][32]
// outp: [8][64][32]
// ---------------------------------------------------------------------------
__global__ void prep_kernel(
    const float* __restrict__ e1w, const float* __restrict__ e2w,
    const float* __restrict__ n1w, const float* __restrict__ n2w,
    const float* __restrict__ outw,
    __bf16* __restrict__ e1p, __bf16* __restrict__ e2p,
    __bf16* __restrict__ n1p, __bf16* __restrict__ n2p,
    __bf16* __restrict__ outp)
{
  int i = blockIdx.x * 256 + threadIdx.x;
  if (i < 3 * 18 * 8192) {
    const int l = i / (18 * 8192), rem = i % (18 * 8192);
    const int c = rem >> 13, r2 = rem & 8191;
    const int n = r2 >> 5, k = c * 32 + (r2 & 31);
    e1p[i] = (k < 560) ? (__bf16)e1w[((size_t)l * 560 + k) * 256 + n] : (__bf16)0.f;
    return;
  }
  i -= 3 * 18 * 8192;
  if (i < 3 * 8 * 8192) {
    const int l = i / 65536, rem = i % 65536;
    const int c = rem >> 13, r2 = rem & 8191;
    const int n = r2 >> 5, k = c * 32 + (r2 & 31);
    e2p[i] = (__bf16)e2w[((size_t)l * 256 + k) * 256 + n];
    return;
  }
  i -= 3 * 8 * 8192;
  if (i < 3 * 17 * 8192) {
    const int l = i / (17 * 8192), rem = i % (17 * 8192);
    const int c = rem >> 13, r2 = rem & 8191;
    const int n = r2 >> 5, k = c * 32 + (r2 & 31);
    n1p[i] = (k < 528) ? (__bf16)n1w[((size_t)l * 528 + k) * 256 + n] : (__bf16)0.f;
    return;
  }
  i -= 3 * 17 * 8192;
  if (i < 3 * 8 * 8192) {
    const int l = i / 65536, rem = i % 65536;
    const int c = rem >> 13, r2 = rem & 8191;
    const int n = r2 >> 5, k = c * 32 + (r2 & 31);
    n2p[i] = (__bf16)n2w[((size_t)l * 256 + k) * 256 + n];
    return;
  }
  i -= 3 * 8 * 8192;
  if (i < 8 * 2048) {
    const int c = i >> 11, r2 = i & 2047;
    const int n = r2 >> 5, k = c * 32 + (r2 & 31);
    outp[i] = (__bf16)outw[(size_t)k * 64 + n];
  }
}

// ---------------------------------------------------------------------------
// Input embedding: h0 = [scalars(16), color(8), role(8)] @ in_w[32,256] + in_b
// 16 nodes/block, 256 threads (thread = output column), fp32 math.
// ---------------------------------------------------------------------------
__global__ __launch_bounds__(256) void embed_kernel(
    const float* __restrict__ scalars, const int* __restrict__ ncol,
    const int* __restrict__ nrole,
    const float* __restrict__ colEmb, const float* __restrict__ roleEmb,
    const float* __restrict__ inw, const float* __restrict__ inb,
    __bf16* __restrict__ h)
{
  __shared__ float sW[32][256];
  __shared__ float sIn[16][32];
  const int tid = threadIdx.x;
  const int n0 = blockIdx.x * 16;
#pragma unroll
  for (int j = 0; j < 32; ++j) sW[j][tid] = inw[j * 256 + tid];
  {
    const int node = tid >> 4, k = tid & 15;
    const int n = n0 + node;
    sIn[node][k] = (n < NN) ? scalars[(size_t)n * 16 + k] : 0.f;
  }
  if (tid < 16) {
    const int n = n0 + tid;
    if (n < NN) {
      const int c = ncol[n], r = nrole[n];
#pragma unroll
      for (int j = 0; j < 8; ++j) {
        sIn[tid][16 + j] = colEmb[c * 8 + j];
        sIn[tid][24 + j] = roleEmb[r * 8 + j];
      }
    } else {
#pragma unroll
      for (int j = 0; j < 16; ++j) sIn[tid][16 + j] = 0.f;
    }
  }
  __syncthreads();
  const float bias = inb[tid];
  for (int nn = 0; nn < 16; ++nn) {
    const int n = n0 + nn;
    if (n >= NN) break;
    float acc = bias;
#pragma unroll
    for (int k = 0; k < 32; ++k) acc += sIn[nn][k] * sW[k][tid];
    h[(size_t)n * H + tid] = (__bf16)acc;
  }
}

__global__ void zero_kernel(float4* __restrict__ p) {
  p[(size_t)blockIdx.x * 256 + threadIdx.x] = make_float4(0.f, 0.f, 0.f, 0.f);
}

// ---------------------------------------------------------------------------
// Fused edge MLP + scatter: per block 64 edges.
//   edge_in[560->576] = [h_src, h_dst, rel, role_s, role_d, col_s, col_d, 0pad]
//   m = silu(edge_in @ e1w + e1b); m = silu(m @ e2w + e2b)
//   atomicAdd into agg[dst]
// 4 waves, wave w owns output cols [64w, 64w+64). A staged in 64-K slices.
// ---------------------------------------------------------------------------
__global__ __launch_bounds__(256, 2) void edge_kernel(
    const __bf16* __restrict__ h, float* __restrict__ agg,
    const int* __restrict__ srcI, const int* __restrict__ dstI,
    const int* __restrict__ erel, const int* __restrict__ nrole,
    const int* __restrict__ ncol,
    const float* __restrict__ relE, const float* __restrict__ roleE,
    const float* __restrict__ colE,
    const __bf16* __restrict__ e1p, const float* __restrict__ e1b,
    const __bf16* __restrict__ e2p, const float* __restrict__ e2b)
{
  __shared__ __align__(16) __bf16 Abuf[64][72];   // 64-K slice, +8 pad (2-way banks)
  __shared__ __align__(16) __bf16 A2[64][264];    // silu(m1), K=256 +8 pad
  __shared__ int sSrc[64], sDst[64];
  __shared__ __bf16 sRel[8][16], sRole[8][8], sCol[3][8];

  const int tid  = threadIdx.x;
  const int lane = tid & 63;
  const int wave = tid >> 6;
  const int l15  = lane & 15;
  const int quad = lane >> 4;
  const int e0   = blockIdx.x * 64;
  const int colW = wave * 64;

  if (tid < 64) { sSrc[tid] = srcI[e0 + tid]; sDst[tid] = dstI[e0 + tid]; }
  if (tid < 128) ((__bf16*)sRel)[tid] = (__bf16)relE[tid];
  else if (tid < 192) ((__bf16*)sRole)[tid - 128] = (__bf16)roleE[tid - 128];
  else if (tid < 216) ((__bf16*)sCol)[tid - 192] = (__bf16)colE[tid - 192];
  __syncthreads();

  f32x4 acc[4][4] = {};
  for (int s = 0; s < 9; ++s) {
    if (s) __syncthreads();
    if (s < 8) {
      const int* idx = (s < 4) ? sSrc : sDst;
      const int colBase = (s & 3) * 64;
#pragma unroll
      for (int it = 0; it < 2; ++it) {
        const int t = tid + it * 256;
        const int row = t >> 3, seg = t & 7;
        const __bf16* p = h + (size_t)idx[row] * H + colBase + seg * 8;
        *(bf16x8*)&Abuf[row][seg * 8] = *(const bf16x8*)p;
      }
    } else {
      const int row = tid >> 2, q = tid & 3;
      __bf16* dp = &Abuf[row][q * 16];
      if (q == 0) {
        const int r = erel[e0 + row];
#pragma unroll
        for (int j = 0; j < 16; ++j) dp[j] = sRel[r][j];
      } else if (q == 1) {
        const int rs = nrole[sSrc[row]], rd = nrole[sDst[row]];
#pragma unroll
        for (int j = 0; j < 8; ++j) { dp[j] = sRole[rs][j]; dp[8 + j] = sRole[rd][j]; }
      } else if (q == 2) {
        const int cs = ncol[sSrc[row]], cd = ncol[sDst[row]];
#pragma unroll
        for (int j = 0; j < 8; ++j) { dp[j] = sCol[cs][j]; dp[8 + j] = sCol[cd][j]; }
      } else {
#pragma unroll
        for (int j = 0; j < 16; ++j) dp[j] = (__bf16)0.f;
      }
    }
    __syncthreads();
#pragma unroll
    for (int cc = 0; cc < 2; ++cc) {
      const int c = 2 * s + cc;
      bf16x8 bfr[4], afr[4];
#pragma unroll
      for (int nj = 0; nj < 4; ++nj)
        bfr[nj] = *(const bf16x8*)(e1p + ((size_t)c * 256 + colW + nj * 16 + l15) * 32 + quad * 8);
#pragma unroll
      for (int mi = 0; mi < 4; ++mi)
        afr[mi] = *(const bf16x8*)&Abuf[mi * 16 + l15][cc * 32 + quad * 8];
#pragma unroll
      for (int mi = 0; mi < 4; ++mi)
#pragma unroll
        for (int nj = 0; nj < 4; ++nj)
          acc[mi][nj] = mfma16(afr[mi], bfr[nj], acc[mi][nj]);
    }
  }

  float b1[4];
#pragma unroll
  for (int nj = 0; nj < 4; ++nj) b1[nj] = e1b[colW + nj * 16 + l15];
#pragma unroll
  for (int mi = 0; mi < 4; ++mi)
#pragma unroll
    for (int nj = 0; nj < 4; ++nj)
#pragma unroll
      for (int r = 0; r < 4; ++r)
        A2[mi * 16 + quad * 4 + r][colW + nj * 16 + l15] =
            (__bf16)silu_f(acc[mi][nj][r] + b1[nj]);
  __syncthreads();

  f32x4 acc2[4][4] = {};
#pragma unroll
  for (int c = 0; c < 8; ++c) {
    bf16x8 bfr[4], afr[4];
#pragma unroll
    for (int nj = 0; nj < 4; ++nj)
      bfr[nj] = *(const bf16x8*)(e2p + ((size_t)c * 256 + colW + nj * 16 + l15) * 32 + quad * 8);
#pragma unroll
    for (int mi = 0; mi < 4; ++mi)
      afr[mi] = *(const bf16x8*)&A2[mi * 16 + l15][c * 32 + quad * 8];
#pragma unroll
    for (int mi = 0; mi < 4; ++mi)
#pragma unroll
      for (int nj = 0; nj < 4; ++nj)
        acc2[mi][nj] = mfma16(afr[mi], bfr[nj], acc2[mi][nj]);
  }

  float b2[4];
#pragma unroll
  for (int nj = 0; nj < 4; ++nj) b2[nj] = e2b[colW + nj * 16 + l15];
#pragma unroll
  for (int mi = 0; mi < 4; ++mi)
#pragma unroll
    for (int r = 0; r < 4; ++r) {
      const int row = mi * 16 + quad * 4 + r;
      float* base = agg + (size_t)sDst[row] * H + colW + l15;
#pragma unroll
      for (int nj = 0; nj < 4; ++nj)
        atomicAdd(base + nj * 16, silu_f(acc2[mi][nj][r] + b2[nj]));
    }
}

// ---------------------------------------------------------------------------
// Fused node update: node_in[528->544] = [h, agg, role, col, 0pad]
//   upd = silu(node_in @ n1w + n1b) @ n2w + n2b ; x = h + upd ; h = LN(x)
// ---------------------------------------------------------------------------
__global__ __launch_bounds__(256, 2) void node_kernel(
    __bf16* __restrict__ h, const float* __restrict__ agg,
    const int* __restrict__ nrole, const int* __restrict__ ncol,
    const float* __restrict__ roleE, const float* __restrict__ colE,
    const __bf16* __restrict__ n1p, const float* __restrict__ n1b,
    const __bf16* __restrict__ n2p, const float* __restrict__ n2b,
    const float* __restrict__ lng, const float* __restrict__ lnb)
{
  __shared__ __align__(16) __bf16 Abuf[64][72];
  __shared__ __align__(16) __bf16 A2[64][264];
  __shared__ __bf16 sRole[8][8], sCol[3][8];
  __shared__ float sSum[64][4], sSsq[64][4];

  const int tid  = threadIdx.x;
  const int lane = tid & 63;
  const int wave = tid >> 6;
  const int l15  = lane & 15;
  const int quad = lane >> 4;
  const int n0   = blockIdx.x * 64;
  const int colW = wave * 64;

  if (tid < 64) ((__bf16*)sRole)[tid] = (__bf16)roleE[tid];
  else if (tid < 88) ((__bf16*)sCol)[tid - 64] = (__bf16)colE[tid - 64];
  __syncthreads();

  f32x4 acc[4][4] = {};
  for (int s = 0; s < 9; ++s) {
    if (s) __syncthreads();
    if (s < 4) {
#pragma unroll
      for (int it = 0; it < 2; ++it) {
        const int t = tid + it * 256;
        const int row = t >> 3, seg = t & 7;
        const int n = n0 + row;
        bf16x8 v = bzero8();
        if (n < NN) v = *(const bf16x8*)(h + (size_t)n * H + s * 64 + seg * 8);
        *(bf16x8*)&Abuf[row][seg * 8] = v;
      }
    } else if (s < 8) {
#pragma unroll
      for (int it = 0; it < 2; ++it) {
        const int t = tid + it * 256;
        const int row = t >> 3, seg = t & 7;
        const int n = n0 + row;
        bf16x8 v = bzero8();
        if (n < NN) {
          const float* p = agg + (size_t)n * H + (s - 4) * 64 + seg * 8;
          const float4 u0 = *(const float4*)p;
          const float4 u1 = *(const float4*)(p + 4);
          v[0] = (__bf16)u0.x; v[1] = (__bf16)u0.y; v[2] = (__bf16)u0.z; v[3] = (__bf16)u0.w;
          v[4] = (__bf16)u1.x; v[5] = (__bf16)u1.y; v[6] = (__bf16)u1.z; v[7] = (__bf16)u1.w;
        }
        *(bf16x8*)&Abuf[row][seg * 8] = v;
      }
    } else {
      const int row = tid >> 2, q = tid & 3;
      const int n = n0 + row;
      __bf16* dp = &Abuf[row][q * 16];
      if (q == 0 && n < NN) {
        const int r = nrole[n], c = ncol[n];
#pragma unroll
        for (int j = 0; j < 8; ++j) { dp[j] = sRole[r][j]; dp[8 + j] = sCol[c][j]; }
      } else {
#pragma unroll
        for (int j = 0; j < 16; ++j) dp[j] = (__bf16)0.f;
      }
    }
    __syncthreads();
#pragma unroll
    for (int cc = 0; cc < 2; ++cc) {
      const int c = 2 * s + cc;
      if (c >= 17) break;
      bf16x8 bfr[4], afr[4];
#pragma unroll
      for (int nj = 0; nj < 4; ++nj)
        bfr[nj] = *(const bf16x8*)(n1p + ((size_t)c * 256 + colW + nj * 16 + l15) * 32 + quad * 8);
#pragma unroll
      for (int mi = 0; mi < 4; ++mi)
        afr[mi] = *(const bf16x8*)&Abuf[mi * 16 + l15][cc * 32 + quad * 8];
#pragma unroll
      for (int mi = 0; mi < 4; ++mi)
#pragma unroll
        for (int nj = 0; nj < 4; ++nj)
          acc[mi][nj] = mfma16(afr[mi], bfr[nj], acc[mi][nj]);
    }
  }

  float b1[4];
#pragma unroll
  for (int nj = 0; nj < 4; ++nj) b1[nj] = n1b[colW + nj * 16 + l15];
#pragma unroll
  for (int mi = 0; mi < 4; ++mi)
#pragma unroll
    for (int nj = 0; nj < 4; ++nj)
#pragma unroll
      for (int r = 0; r < 4; ++r)
        A2[mi * 16 + quad * 4 + r][colW + nj * 16 + l15] =
            (__bf16)silu_f(acc[mi][nj][r] + b1[nj]);
  __syncthreads();

  f32x4 acc2[4][4] = {};
#pragma unroll
  for (int c = 0; c < 8; ++c) {
    bf16x8 bfr[4], afr[4];
#pragma unroll
    for (int nj = 0; nj < 4; ++nj)
      bfr[nj] = *(const bf16x8*)(n2p + ((size_t)c * 256 + colW + nj * 16 + l15) * 32 + quad * 8);
#pragma unroll
    for (int mi = 0; mi < 4; ++mi)
      afr[mi] = *(const bf16x8*)&A2[mi * 16 + l15][c * 32 + quad * 8];
#pragma unroll
    for (int mi = 0; mi < 4; ++mi)
#pragma unroll
      for (int nj = 0; nj < 4; ++nj)
        acc2[mi][nj] = mfma16(afr[mi], bfr[nj], acc2[mi][nj]);
  }

  float b2[4], g4[4], bb4[4];
#pragma unroll
  for (int nj = 0; nj < 4; ++nj) {
    const int col = colW + nj * 16 + l15;
    b2[nj] = n2b[col]; g4[nj] = lng[col]; bb4[nj] = lnb[col];
  }
  // x = h + upd (into acc2)
#pragma unroll
  for (int mi = 0; mi < 4; ++mi)
#pragma unroll
    for (int r = 0; r < 4; ++r) {
      const int n = n0 + mi * 16 + quad * 4 + r;
#pragma unroll
      for (int nj = 0; nj < 4; ++nj) {
        const float hv = (n < NN) ? (float)h[(size_t)n * H + colW + nj * 16 + l15] : 0.f;
        acc2[mi][nj][r] += b2[nj] + hv;
      }
    }
  // LayerNorm: row sums within wave (16-lane shfl) then across waves (LDS)
#pragma unroll
  for (int mi = 0; mi < 4; ++mi)
#pragma unroll
    for (int r = 0; r < 4; ++r) {
      float s1 = 0.f, s2 = 0.f;
#pragma unroll
      for (int nj = 0; nj < 4; ++nj) {
        const float v = acc2[mi][nj][r];
        s1 += v; s2 += v * v;
      }
#pragma unroll
      for (int d = 1; d < 16; d <<= 1) {
        s1 += __shfl_xor(s1, d, 16);
        s2 += __shfl_xor(s2, d, 16);
      }
      if (l15 == 0) {
        const int row = mi * 16 + quad * 4 + r;
        sSum[row][wave] = s1; sSsq[row][wave] = s2;
      }
    }
  __syncthreads();
#pragma unroll
  for (int mi = 0; mi < 4; ++mi)
#pragma unroll
    for (int r = 0; r < 4; ++r) {
      const int row = mi * 16 + quad * 4 + r;
      const int n = n0 + row;
      const float t1 = sSum[row][0] + sSum[row][1] + sSum[row][2] + sSum[row][3];
      const float t2 = sSsq[row][0] + sSsq[row][1] + sSsq[row][2] + sSsq[row][3];
      const float mu = t1 * (1.f / 256.f);
      float var = t2 * (1.f / 256.f) - mu * mu;
      var = var < 0.f ? 0.f : var;
      const float rstd = rsqrtf(var + 1e-5f);
      if (n < NN) {
#pragma unroll
        for (int nj = 0; nj < 4; ++nj) {
          const float o = g4[nj] * (acc2[mi][nj][r] - mu) * rstd + bb4[nj];
          h[(size_t)n * H + colW + nj * 16 + l15] = (__bf16)o;
        }
      }
    }
}

// ---------------------------------------------------------------------------
// Output projection: out = h @ out_w[256,64] + out_b, fp32 output.
// 64 rows/block, wave w owns rows [16w,16w+16), all 64 cols.
// ---------------------------------------------------------------------------
__global__ __launch_bounds__(256) void out_kernel(
    const __bf16* __restrict__ h, const __bf16* __restrict__ outp,
    const float* __restrict__ outb, float* __restrict__ out)
{
  const int tid  = threadIdx.x;
  const int lane = tid & 63;
  const int wave = tid >> 6;
  const int l15  = lane & 15;
  const int quad = lane >> 4;
  const int m0   = blockIdx.x * 64 + wave * 16;
  int ar = m0 + l15;
  if (ar >= NN) ar = NN - 1;
  f32x4 acc[4] = {};
#pragma unroll
  for (int c = 0; c < 8; ++c) {
    const bf16x8 a = *(const bf16x8*)(h + (size_t)ar * H + c * 32 + quad * 8);
#pragma unroll
    for (int nj = 0; nj < 4; ++nj) {
      const bf16x8 b = *(const bf16x8*)(outp + ((size_t)c * 64 + nj * 16 + l15) * 32 + quad * 8);
      acc[nj] = mfma16(a, b, acc[nj]);
    }
  }
#pragma unroll
  for (int nj = 0; nj < 4; ++nj) {
    const float bb = outb[nj * 16 + l15];
#pragma unroll
    for (int r = 0; r < 4; ++r) {
      const int row = m0 + quad * 4 + r;
      if (row < NN) out[(size_t)row * 64 + nj * 16 + l15] = acc[nj][r] + bb;
    }
  }
}

// ---------------------------------------------------------------------------
extern "C" void kernel_launch(void* const* d_in, const int* in_sizes, int n_in,
                              void* d_out, int out_size, void* d_ws, size_t ws_size,
                              hipStream_t stream) {
  const float* scalars   = (const float*)d_in[0];
  const int*   ei        = (const int*)d_in[1];
  const int*   erel      = (const int*)d_in[2];
  const int*   ncol      = (const int*)d_in[3];
  const int*   nrole     = (const int*)d_in[4];
  const float* blk_role  = (const float*)d_in[5];
  const float* blk_col   = (const float*)d_in[6];
  const float* inw       = (const float*)d_in[7];
  const float* inb       = (const float*)d_in[8];
  const float* rel_embs  = (const float*)d_in[9];
  const float* role_embs = (const float*)d_in[10];
  const float* col_embs  = (const float*)d_in[11];
  const float* e1w       = (const float*)d_in[12];
  const float* e1b       = (const float*)d_in[13];
  const float* e2w       = (const float*)d_in[14];
  const float* e2b       = (const float*)d_in[15];
  const float* n1w       = (const float*)d_in[16];
  const float* n1b       = (const float*)d_in[17];
  const float* n2w       = (const float*)d_in[18];
  const float* n2b       = (const float*)d_in[19];
  const float* lng       = (const float*)d_in[20];
  const float* lnb       = (const float*)d_in[21];
  const float* outw      = (const float*)d_in[22];
  const float* outb      = (const float*)d_in[23];

  const int* srcI = ei;
  const int* dstI = ei + NE;

  char* ws = (char*)d_ws;
  size_t off = 0;
  auto take = [&](size_t bytes) -> char* {
    off = (off + 255) & ~(size_t)255;
    char* p = ws + off;
    off += bytes;
    return p;
  };
  __bf16* h    = (__bf16*)take((size_t)NN * H * 2);
  float*  agg  = (float*)take((size_t)NN * H * 4);
  __bf16* e1p  = (__bf16*)take((size_t)3 * 18 * 8192 * 2);
  __bf16* e2p  = (__bf16*)take((size_t)3 * 8 * 8192 * 2);
  __bf16* n1p  = (__bf16*)take((size_t)3 * 17 * 8192 * 2);
  __bf16* n2p  = (__bf16*)take((size_t)3 * 8 * 8192 * 2);
  __bf16* outp = (__bf16*)take((size_t)8 * 2048 * 2);

  prep_kernel<<<4960, 256, 0, stream>>>(e1w, e2w, n1w, n2w, outw,
                                        e1p, e2p, n1p, n2p, outp);
  embed_kernel<<<(NN + 15) / 16, 256, 0, stream>>>(scalars, ncol, nrole,
                                                   blk_col, blk_role, inw, inb, h);
  for (int l = 0; l < 3; ++l) {
    zero_kernel<<<(NN * H) / (256 * 4), 256, 0, stream>>>((float4*)agg);
    edge_kernel<<<NE / 64, 256, 0, stream>>>(
        h, agg, srcI, dstI, erel, nrole, ncol,
        rel_embs + (size_t)l * 128, role_embs + (size_t)l * 64, col_embs + (size_t)l * 24,
        e1p + (size_t)l * 18 * 8192, e1b + (size_t)l * 256,
        e2p + (size_t)l * 8 * 8192,  e2b + (size_t)l * 256);
    node_kernel<<<(NN + 63) / 64, 256, 0, stream>>>(
        h, agg, nrole, ncol,
        role_embs + (size_t)l * 64, col_embs + (size_t)l * 24,
        n1p + (size_t)l * 17 * 8192, n1b + (size_t)l * 256,
        n2p + (size_t)l * 8 * 8192,  n2b + (size_t)l * 256,
        lng + (size_t)l * 256, lnb + (size_t)l * 256);
  }
  out_kernel<<<(NN + 63) / 64, 256, 0, stream>>>(h, outp, outb, (float*)d_out);
}

// Round 2
// 2062.770 us; speedup vs baseline: 1.3345x; 1.3345x over previous
//
#include <hip/hip_runtime.h>

#define NN 50000
#define NE 800000
#define H 256
#define NBINS 50176   // NN padded to 196*256

typedef __bf16 bf16x8 __attribute__((ext_vector_type(8)));
typedef float f32x4 __attribute__((ext_vector_type(4)));

static __device__ __forceinline__ f32x4 mfma16(bf16x8 a, bf16x8 b, f32x4 c) {
  return __builtin_amdgcn_mfma_f32_16x16x32_bf16(a, b, c, 0, 0, 0);
}
static __device__ __forceinline__ bf16x8 bzero8() {
  bf16x8 z;
#pragma unroll
  for (int j = 0; j < 8; ++j) z[j] = (__bf16)0.f;
  return z;
}
static __device__ __forceinline__ float silu_f(float v) {
  return v / (1.f + __expf(-v));
}

// ---------------------------------------------------------------------------
// Weight prep: fp32 -> bf16, K padded to mult of 32, layout [chunk][n][32k].
// ---------------------------------------------------------------------------
__global__ void prep_kernel(
    const float* __restrict__ e1w, const float* __restrict__ e2w,
    const float* __restrict__ n1w, const float* __restrict__ n2w,
    const float* __restrict__ outw,
    __bf16* __restrict__ e1p, __bf16* __restrict__ e2p,
    __bf16* __restrict__ n1p, __bf16* __restrict__ n2p,
    __bf16* __restrict__ outp)
{
  int i = blockIdx.x * 256 + threadIdx.x;
  if (i < 3 * 18 * 8192) {
    const int l = i / (18 * 8192), rem = i % (18 * 8192);
    const int c = rem >> 13, r2 = rem & 8191;
    const int n = r2 >> 5, k = c * 32 + (r2 & 31);
    e1p[i] = (k < 560) ? (__bf16)e1w[((size_t)l * 560 + k) * 256 + n] : (__bf16)0.f;
    return;
  }
  i -= 3 * 18 * 8192;
  if (i < 3 * 8 * 8192) {
    const int l = i / 65536, rem = i % 65536;
    const int c = rem >> 13, r2 = rem & 8191;
    const int n = r2 >> 5, k = c * 32 + (r2 & 31);
    e2p[i] = (__bf16)e2w[((size_t)l * 256 + k) * 256 + n];
    return;
  }
  i -= 3 * 8 * 8192;
  if (i < 3 * 17 * 8192) {
    const int l = i / (17 * 8192), rem = i % (17 * 8192);
    const int c = rem >> 13, r2 = rem & 8191;
    const int n = r2 >> 5, k = c * 32 + (r2 & 31);
    n1p[i] = (k < 528) ? (__bf16)n1w[((size_t)l * 528 + k) * 256 + n] : (__bf16)0.f;
    return;
  }
  i -= 3 * 17 * 8192;
  if (i < 3 * 8 * 8192) {
    const int l = i / 65536, rem = i % 65536;
    const int c = rem >> 13, r2 = rem & 8191;
    const int n = r2 >> 5, k = c * 32 + (r2 & 31);
    n2p[i] = (__bf16)n2w[((size_t)l * 256 + k) * 256 + n];
    return;
  }
  i -= 3 * 8 * 8192;
  if (i < 8 * 2048) {
    const int c = i >> 11, r2 = i & 2047;
    const int n = r2 >> 5, k = c * 32 + (r2 & 31);
    outp[i] = (__bf16)outw[(size_t)k * 64 + n];
  }
}

// ---------------------------------------------------------------------------
// Counting sort of edges by dst: hist -> exclusive scan -> scatter.
// ---------------------------------------------------------------------------
__global__ void hist_kernel(const int* __restrict__ dstI, int* __restrict__ cnt) {
  const int e = blockIdx.x * 256 + threadIdx.x;
  if (e < NE) atomicAdd(&cnt[dstI[e]], 1);
}

__global__ __launch_bounds__(256) void scan_kernel(int* __restrict__ cnt) {
  __shared__ int wsum[4];
  __shared__ int sCarry;
  const int tid = threadIdx.x, lane = tid & 63, wid = tid >> 6;
  if (tid == 0) sCarry = 0;
  __syncthreads();
  for (int base = 0; base < NBINS; base += 256) {
    const int i = base + tid;
    const int v = cnt[i];
    int x = v;
#pragma unroll
    for (int d = 1; d < 64; d <<= 1) {
      const int y = __shfl_up(x, d, 64);
      if (lane >= d) x += y;
    }
    if (lane == 63) wsum[wid] = x;
    __syncthreads();
    int wpref = 0;
#pragma unroll
    for (int w = 0; w < 4; ++w)
      if (w < wid) wpref += wsum[w];
    cnt[i] = sCarry + wpref + x - v;   // exclusive prefix
    __syncthreads();
    if (tid == 0) sCarry += wsum[0] + wsum[1] + wsum[2] + wsum[3];
    __syncthreads();
  }
}

__global__ void scatter_kernel(const int* __restrict__ srcI, const int* __restrict__ dstI,
                               const int* __restrict__ erel, int* __restrict__ cnt,
                               int* __restrict__ srcS, int* __restrict__ dstS,
                               int* __restrict__ relS) {
  const int e = blockIdx.x * 256 + threadIdx.x;
  if (e < NE) {
    const int d = dstI[e];
    const int pos = atomicAdd(&cnt[d], 1);
    srcS[pos] = srcI[e];
    dstS[pos] = d;
    relS[pos] = erel[e];
  }
}

// ---------------------------------------------------------------------------
// Input embedding.
// ---------------------------------------------------------------------------
__global__ __launch_bounds__(256) void embed_kernel(
    const float* __restrict__ scalars, const int* __restrict__ ncol,
    const int* __restrict__ nrole,
    const float* __restrict__ colEmb, const float* __restrict__ roleEmb,
    const float* __restrict__ inw, const float* __restrict__ inb,
    __bf16* __restrict__ h)
{
  __shared__ float sW[32][256];
  __shared__ float sIn[16][32];
  const int tid = threadIdx.x;
  const int n0 = blockIdx.x * 16;
#pragma unroll
  for (int j = 0; j < 32; ++j) sW[j][tid] = inw[j * 256 + tid];
  {
    const int node = tid >> 4, k = tid & 15;
    const int n = n0 + node;
    sIn[node][k] = (n < NN) ? scalars[(size_t)n * 16 + k] : 0.f;
  }
  if (tid < 16) {
    const int n = n0 + tid;
    if (n < NN) {
      const int c = ncol[n], r = nrole[n];
#pragma unroll
      for (int j = 0; j < 8; ++j) {
        sIn[tid][16 + j] = colEmb[c * 8 + j];
        sIn[tid][24 + j] = roleEmb[r * 8 + j];
      }
    } else {
#pragma unroll
      for (int j = 0; j < 16; ++j) sIn[tid][16 + j] = 0.f;
    }
  }
  __syncthreads();
  const float bias = inb[tid];
  for (int nn = 0; nn < 16; ++nn) {
    const int n = n0 + nn;
    if (n >= NN) break;
    float acc = bias;
#pragma unroll
    for (int k = 0; k < 32; ++k) acc += sIn[nn][k] * sW[k][tid];
    h[(size_t)n * H + tid] = (__bf16)acc;
  }
}

// ---------------------------------------------------------------------------
// Fused edge MLP + segmented scatter. Edges sorted by dst.
// Pipelined A staging (double-buffered LDS), m written back to A2 (bf16),
// per-column segmented reduce, one atomicAdd per (dst-segment, column).
// ---------------------------------------------------------------------------
__global__ __launch_bounds__(256, 2) void edge_kernel(
    const __bf16* __restrict__ h, float* __restrict__ agg,
    const int* __restrict__ srcS, const int* __restrict__ dstS,
    const int* __restrict__ relS, const int* __restrict__ nrole,
    const int* __restrict__ ncol,
    const float* __restrict__ relE, const float* __restrict__ roleE,
    const float* __restrict__ colE,
    const __bf16* __restrict__ e1p, const float* __restrict__ e1b,
    const __bf16* __restrict__ e2p, const float* __restrict__ e2b)
{
  __shared__ __align__(16) __bf16 Ab[2][64][72];
  __shared__ __align__(16) __bf16 A2[64][264];
  __shared__ int sSrc[64], sDst[64];
  __shared__ __bf16 sRel[8][16], sRole[8][8], sCol[3][8];

  const int tid  = threadIdx.x;
  const int lane = tid & 63;
  const int wave = tid >> 6;
  const int l15  = lane & 15;
  const int quad = lane >> 4;
  const int e0   = blockIdx.x * 64;
  const int colW = wave * 64;

  if (tid < 64) { sSrc[tid] = srcS[e0 + tid]; sDst[tid] = dstS[e0 + tid]; }
  if (tid < 128) ((__bf16*)sRel)[tid] = (__bf16)relE[tid];
  else if (tid < 192) ((__bf16*)sRole)[tid - 128] = (__bf16)roleE[tid - 128];
  else if (tid < 216) ((__bf16*)sCol)[tid - 192] = (__bf16)colE[tid - 192];
  __syncthreads();

  // ---- embed fill into Ab[0] (global K 512..575 -> chunks 16,17) ----
  {
    const int row = tid >> 2, q = tid & 3;
    __bf16* dp = &Ab[0][row][q * 16];
    if (q == 0) {
      const int r = relS[e0 + row];
#pragma unroll
      for (int j = 0; j < 16; ++j) dp[j] = sRel[r][j];
    } else if (q == 1) {
      const int rs = nrole[sSrc[row]], rd = nrole[sDst[row]];
#pragma unroll
      for (int j = 0; j < 8; ++j) { dp[j] = sRole[rs][j]; dp[8 + j] = sRole[rd][j]; }
    } else if (q == 2) {
      const int cs = ncol[sSrc[row]], cd = ncol[sDst[row]];
#pragma unroll
      for (int j = 0; j < 8; ++j) { dp[j] = sCol[cs][j]; dp[8 + j] = sCol[cd][j]; }
    } else {
#pragma unroll
      for (int j = 0; j < 16; ++j) dp[j] = (__bf16)0.f;
    }
  }

  const int rowA = tid >> 3;          // 0..31
  const int segO = (tid & 7) * 8;     // col offset in 64-wide slice
  bf16x8 rg0, rg1;
  auto issue = [&](int t) {
    const int* idx = (t < 4) ? sSrc : sDst;
    const int cb = (t & 3) * 64 + segO;
    rg0 = *(const bf16x8*)(h + (size_t)idx[rowA] * H + cb);
    rg1 = *(const bf16x8*)(h + (size_t)idx[rowA + 32] * H + cb);
  };

  f32x4 acc[4][4] = {};
  auto compute2 = [&](const __bf16 (*Abuf)[72], int c0) {
#pragma unroll
    for (int cc = 0; cc < 2; ++cc) {
      const int c = c0 + cc;
      bf16x8 bfr[4], afr[4];
#pragma unroll
      for (int nj = 0; nj < 4; ++nj)
        bfr[nj] = *(const bf16x8*)(e1p + ((size_t)c * 256 + colW + nj * 16 + l15) * 32 + quad * 8);
#pragma unroll
      for (int mi = 0; mi < 4; ++mi)
        afr[mi] = *(const bf16x8*)&Abuf[mi * 16 + l15][cc * 32 + quad * 8];
#pragma unroll
      for (int mi = 0; mi < 4; ++mi)
#pragma unroll
        for (int nj = 0; nj < 4; ++nj)
          acc[mi][nj] = mfma16(afr[mi], bfr[nj], acc[mi][nj]);
    }
  };

  issue(0);              // stage-0 gathers in flight during embed compute
  __syncthreads();       // Ab[0] (embeds) ready
  compute2(Ab[0], 16);   // chunks 16,17
  *(bf16x8*)&Ab[1][rowA][segO] = rg0;        // waits vmcnt internally
  *(bf16x8*)&Ab[1][rowA + 32][segO] = rg1;
  __syncthreads();       // Ab[1] (stage 0) ready

  for (int t = 0; t < 8; ++t) {
    if (t < 7) issue(t + 1);
    compute2(Ab[(t + 1) & 1], 2 * t);
    if (t < 7) {
      const int b = t & 1;
      *(bf16x8*)&Ab[b][rowA][segO] = rg0;
      *(bf16x8*)&Ab[b][rowA + 32][segO] = rg1;
      __syncthreads();
    }
  }

  // ---- epilogue GEMM1: silu -> A2 (bf16) ----
  float b1[4];
#pragma unroll
  for (int nj = 0; nj < 4; ++nj) b1[nj] = e1b[colW + nj * 16 + l15];
#pragma unroll
  for (int mi = 0; mi < 4; ++mi)
#pragma unroll
    for (int nj = 0; nj < 4; ++nj)
#pragma unroll
      for (int r = 0; r < 4; ++r)
        A2[mi * 16 + quad * 4 + r][colW + nj * 16 + l15] =
            (__bf16)silu_f(acc[mi][nj][r] + b1[nj]);
  __syncthreads();

  // ---- GEMM2 ----
  f32x4 acc2[4][4] = {};
#pragma unroll
  for (int c = 0; c < 8; ++c) {
    bf16x8 bfr[4], afr[4];
#pragma unroll
    for (int nj = 0; nj < 4; ++nj)
      bfr[nj] = *(const bf16x8*)(e2p + ((size_t)c * 256 + colW + nj * 16 + l15) * 32 + quad * 8);
#pragma unroll
    for (int mi = 0; mi < 4; ++mi)
      afr[mi] = *(const bf16x8*)&A2[mi * 16 + l15][c * 32 + quad * 8];
#pragma unroll
    for (int mi = 0; mi < 4; ++mi)
#pragma unroll
      for (int nj = 0; nj < 4; ++nj)
        acc2[mi][nj] = mfma16(afr[mi], bfr[nj], acc2[mi][nj]);
  }

  // ---- write m (bf16) back into A2, then per-column segmented reduce ----
  float b2[4];
#pragma unroll
  for (int nj = 0; nj < 4; ++nj) b2[nj] = e2b[colW + nj * 16 + l15];
  __syncthreads();   // all waves done reading A2
#pragma unroll
  for (int mi = 0; mi < 4; ++mi)
#pragma unroll
    for (int nj = 0; nj < 4; ++nj)
#pragma unroll
      for (int r = 0; r < 4; ++r)
        A2[mi * 16 + quad * 4 + r][colW + nj * 16 + l15] =
            (__bf16)silu_f(acc2[mi][nj][r] + b2[nj]);
  __syncthreads();

  {
    const int col = tid;                    // 256 threads = 256 columns
    float sum = (float)A2[0][col];
    int cur = sDst[0];                      // uniform broadcast
    for (int r = 1; r < 64; ++r) {
      const int dn = sDst[r];
      const float v = (float)A2[r][col];
      if (dn != cur) {                      // wave-uniform branch
        atomicAdd(agg + (size_t)cur * H + col, sum);
        sum = v; cur = dn;
      } else {
        sum += v;
      }
    }
    atomicAdd(agg + (size_t)cur * H + col, sum);
  }
}

// ---------------------------------------------------------------------------
// Fused node update (unchanged from round 0).
// ---------------------------------------------------------------------------
__global__ __launch_bounds__(256, 2) void node_kernel(
    __bf16* __restrict__ h, const float* __restrict__ agg,
    const int* __restrict__ nrole, const int* __restrict__ ncol,
    const float* __restrict__ roleE, const float* __restrict__ colE,
    const __bf16* __restrict__ n1p, const float* __restrict__ n1b,
    const __bf16* __restrict__ n2p, const float* __restrict__ n2b,
    const float* __restrict__ lng, const float* __restrict__ lnb)
{
  __shared__ __align__(16) __bf16 Abuf[64][72];
  __shared__ __align__(16) __bf16 A2[64][264];
  __shared__ __bf16 sRole[8][8], sCol[3][8];
  __shared__ float sSum[64][4], sSsq[64][4];

  const int tid  = threadIdx.x;
  const int lane = tid & 63;
  const int wave = tid >> 6;
  const int l15  = lane & 15;
  const int quad = lane >> 4;
  const int n0   = blockIdx.x * 64;
  const int colW = wave * 64;

  if (tid < 64) ((__bf16*)sRole)[tid] = (__bf16)roleE[tid];
  else if (tid < 88) ((__bf16*)sCol)[tid - 64] = (__bf16)colE[tid - 64];
  __syncthreads();

  f32x4 acc[4][4] = {};
  for (int s = 0; s < 9; ++s) {
    if (s) __syncthreads();
    if (s < 4) {
#pragma unroll
      for (int it = 0; it < 2; ++it) {
        const int t = tid + it * 256;
        const int row = t >> 3, seg = t & 7;
        const int n = n0 + row;
        bf16x8 v = bzero8();
        if (n < NN) v = *(const bf16x8*)(h + (size_t)n * H + s * 64 + seg * 8);
        *(bf16x8*)&Abuf[row][seg * 8] = v;
      }
    } else if (s < 8) {
#pragma unroll
      for (int it = 0; it < 2; ++it) {
        const int t = tid + it * 256;
        const int row = t >> 3, seg = t & 7;
        const int n = n0 + row;
        bf16x8 v = bzero8();
        if (n < NN) {
          const float* p = agg + (size_t)n * H + (s - 4) * 64 + seg * 8;
          const float4 u0 = *(const float4*)p;
          const float4 u1 = *(const float4*)(p + 4);
          v[0] = (__bf16)u0.x; v[1] = (__bf16)u0.y; v[2] = (__bf16)u0.z; v[3] = (__bf16)u0.w;
          v[4] = (__bf16)u1.x; v[5] = (__bf16)u1.y; v[6] = (__bf16)u1.z; v[7] = (__bf16)u1.w;
        }
        *(bf16x8*)&Abuf[row][seg * 8] = v;
      }
    } else {
      const int row = tid >> 2, q = tid & 3;
      const int n = n0 + row;
      __bf16* dp = &Abuf[row][q * 16];
      if (q == 0 && n < NN) {
        const int r = nrole[n], c = ncol[n];
#pragma unroll
        for (int j = 0; j < 8; ++j) { dp[j] = sRole[r][j]; dp[8 + j] = sCol[c][j]; }
      } else {
#pragma unroll
        for (int j = 0; j < 16; ++j) dp[j] = (__bf16)0.f;
      }
    }
    __syncthreads();
#pragma unroll
    for (int cc = 0; cc < 2; ++cc) {
      const int c = 2 * s + cc;
      if (c >= 17) break;
      bf16x8 bfr[4], afr[4];
#pragma unroll
      for (int nj = 0; nj < 4; ++nj)
        bfr[nj] = *(const bf16x8*)(n1p + ((size_t)c * 256 + colW + nj * 16 + l15) * 32 + quad * 8);
#pragma unroll
      for (int mi = 0; mi < 4; ++mi)
        afr[mi] = *(const bf16x8*)&Abuf[mi * 16 + l15][cc * 32 + quad * 8];
#pragma unroll
      for (int mi = 0; mi < 4; ++mi)
#pragma unroll
        for (int nj = 0; nj < 4; ++nj)
          acc[mi][nj] = mfma16(afr[mi], bfr[nj], acc[mi][nj]);
    }
  }

  float b1[4];
#pragma unroll
  for (int nj = 0; nj < 4; ++nj) b1[nj] = n1b[colW + nj * 16 + l15];
#pragma unroll
  for (int mi = 0; mi < 4; ++mi)
#pragma unroll
    for (int nj = 0; nj < 4; ++nj)
#pragma unroll
      for (int r = 0; r < 4; ++r)
        A2[mi * 16 + quad * 4 + r][colW + nj * 16 + l15] =
            (__bf16)silu_f(acc[mi][nj][r] + b1[nj]);
  __syncthreads();

  f32x4 acc2[4][4] = {};
#pragma unroll
  for (int c = 0; c < 8; ++c) {
    bf16x8 bfr[4], afr[4];
#pragma unroll
    for (int nj = 0; nj < 4; ++nj)
      bfr[nj] = *(const bf16x8*)(n2p + ((size_t)c * 256 + colW + nj * 16 + l15) * 32 + quad * 8);
#pragma unroll
    for (int mi = 0; mi < 4; ++mi)
      afr[mi] = *(const bf16x8*)&A2[mi * 16 + l15][c * 32 + quad * 8];
#pragma unroll
    for (int mi = 0; mi < 4; ++mi)
#pragma unroll
      for (int nj = 0; nj < 4; ++nj)
        acc2[mi][nj] = mfma16(afr[mi], bfr[nj], acc2[mi][nj]);
  }

  float b2[4], g4[4], bb4[4];
#pragma unroll
  for (int nj = 0; nj < 4; ++nj) {
    const int col = colW + nj * 16 + l15;
    b2[nj] = n2b[col]; g4[nj] = lng[col]; bb4[nj] = lnb[col];
  }
#pragma unroll
  for (int mi = 0; mi < 4; ++mi)
#pragma unroll
    for (int r = 0; r < 4; ++r) {
      const int n = n0 + mi * 16 + quad * 4 + r;
#pragma unroll
      for (int nj = 0; nj < 4; ++nj) {
        const float hv = (n < NN) ? (float)h[(size_t)n * H + colW + nj * 16 + l15] : 0.f;
        acc2[mi][nj][r] += b2[nj] + hv;
      }
    }
#pragma unroll
  for (int mi = 0; mi < 4; ++mi)
#pragma unroll
    for (int r = 0; r < 4; ++r) {
      float s1 = 0.f, s2 = 0.f;
#pragma unroll
      for (int nj = 0; nj < 4; ++nj) {
        const float v = acc2[mi][nj][r];
        s1 += v; s2 += v * v;
      }
#pragma unroll
      for (int d = 1; d < 16; d <<= 1) {
        s1 += __shfl_xor(s1, d, 16);
        s2 += __shfl_xor(s2, d, 16);
      }
      if (l15 == 0) {
        const int row = mi * 16 + quad * 4 + r;
        sSum[row][wave] = s1; sSsq[row][wave] = s2;
      }
    }
  __syncthreads();
#pragma unroll
  for (int mi = 0; mi < 4; ++mi)
#pragma unroll
    for (int r = 0; r < 4; ++r) {
      const int row = mi * 16 + quad * 4 + r;
      const int n = n0 + row;
      const float t1 = sSum[row][0] + sSum[row][1] + sSum[row][2] + sSum[row][3];
      const float t2 = sSsq[row][0] + sSsq[row][1] + sSsq[row][2] + sSsq[row][3];
      const float mu = t1 * (1.f / 256.f);
      float var = t2 * (1.f / 256.f) - mu * mu;
      var = var < 0.f ? 0.f : var;
      const float rstd = rsqrtf(var + 1e-5f);
      if (n < NN) {
#pragma unroll
        for (int nj = 0; nj < 4; ++nj) {
          const float o = g4[nj] * (acc2[mi][nj][r] - mu) * rstd + bb4[nj];
          h[(size_t)n * H + colW + nj * 16 + l15] = (__bf16)o;
        }
      }
    }
}

// ---------------------------------------------------------------------------
// Output projection.
// ---------------------------------------------------------------------------
__global__ __launch_bounds__(256) void out_kernel(
    const __bf16* __restrict__ h, const __bf16* __restrict__ outp,
    const float* __restrict__ outb, float* __restrict__ out)
{
  const int tid  = threadIdx.x;
  const int lane = tid & 63;
  const int wave = tid >> 6;
  const int l15  = lane & 15;
  const int quad = lane >> 4;
  const int m0   = blockIdx.x * 64 + wave * 16;
  int ar = m0 + l15;
  if (ar >= NN) ar = NN - 1;
  f32x4 acc[4] = {};
#pragma unroll
  for (int c = 0; c < 8; ++c) {
    const bf16x8 a = *(const bf16x8*)(h + (size_t)ar * H + c * 32 + quad * 8);
#pragma unroll
    for (int nj = 0; nj < 4; ++nj) {
      const bf16x8 b = *(const bf16x8*)(outp + ((size_t)c * 64 + nj * 16 + l15) * 32 + quad * 8);
      acc[nj] = mfma16(a, b, acc[nj]);
    }
  }
#pragma unroll
  for (int nj = 0; nj < 4; ++nj) {
    const float bb = outb[nj * 16 + l15];
#pragma unroll
    for (int r = 0; r < 4; ++r) {
      const int row = m0 + quad * 4 + r;
      if (row < NN) out[(size_t)row * 64 + nj * 16 + l15] = acc[nj][r] + bb;
    }
  }
}

// ---------------------------------------------------------------------------
extern "C" void kernel_launch(void* const* d_in, const int* in_sizes, int n_in,
                              void* d_out, int out_size, void* d_ws, size_t ws_size,
                              hipStream_t stream) {
  const float* scalars   = (const float*)d_in[0];
  const int*   ei        = (const int*)d_in[1];
  const int*   erel      = (const int*)d_in[2];
  const int*   ncol      = (const int*)d_in[3];
  const int*   nrole     = (const int*)d_in[4];
  const float* blk_role  = (const float*)d_in[5];
  const float* blk_col   = (const float*)d_in[6];
  const float* inw       = (const float*)d_in[7];
  const float* inb       = (const float*)d_in[8];
  const float* rel_embs  = (const float*)d_in[9];
  const float* role_embs = (const float*)d_in[10];
  const float* col_embs  = (const float*)d_in[11];
  const float* e1w       = (const float*)d_in[12];
  const float* e1b       = (const float*)d_in[13];
  const float* e2w       = (const float*)d_in[14];
  const float* e2b       = (const float*)d_in[15];
  const float* n1w       = (const float*)d_in[16];
  const float* n1b       = (const float*)d_in[17];
  const float* n2w       = (const float*)d_in[18];
  const float* n2b       = (const float*)d_in[19];
  const float* lng       = (const float*)d_in[20];
  const float* lnb       = (const float*)d_in[21];
  const float* outw      = (const float*)d_in[22];
  const float* outb      = (const float*)d_in[23];

  const int* srcI = ei;
  const int* dstI = ei + NE;

  char* ws = (char*)d_ws;
  size_t off = 0;
  auto take = [&](size_t bytes) -> char* {
    off = (off + 255) & ~(size_t)255;
    char* p = ws + off;
    off += bytes;
    return p;
  };
  __bf16* h    = (__bf16*)take((size_t)NN * H * 2);
  float*  agg  = (float*)take((size_t)NN * H * 4);
  __bf16* e1p  = (__bf16*)take((size_t)3 * 18 * 8192 * 2);
  __bf16* e2p  = (__bf16*)take((size_t)3 * 8 * 8192 * 2);
  __bf16* n1p  = (__bf16*)take((size_t)3 * 17 * 8192 * 2);
  __bf16* n2p  = (__bf16*)take((size_t)3 * 8 * 8192 * 2);
  __bf16* outp = (__bf16*)take((size_t)8 * 2048 * 2);
  int*    cnt  = (int*)take((size_t)NBINS * 4);
  int*    srcS = (int*)take((size_t)NE * 4);
  int*    dstS = (int*)take((size_t)NE * 4);
  int*    relS = (int*)take((size_t)NE * 4);

  prep_kernel<<<4960, 256, 0, stream>>>(e1w, e2w, n1w, n2w, outw,
                                        e1p, e2p, n1p, n2p, outp);
  embed_kernel<<<(NN + 15) / 16, 256, 0, stream>>>(scalars, ncol, nrole,
                                                   blk_col, blk_role, inw, inb, h);
  // counting sort of edges by dst
  hipMemsetAsync(cnt, 0, (size_t)NBINS * 4, stream);
  hist_kernel<<<(NE + 255) / 256, 256, 0, stream>>>(dstI, cnt);
  scan_kernel<<<1, 256, 0, stream>>>(cnt);
  scatter_kernel<<<(NE + 255) / 256, 256, 0, stream>>>(srcI, dstI, erel, cnt,
                                                       srcS, dstS, relS);

  for (int l = 0; l < 3; ++l) {
    hipMemsetAsync(agg, 0, (size_t)NN * H * 4, stream);
    edge_kernel<<<NE / 64, 256, 0, stream>>>(
        h, agg, srcS, dstS, relS, nrole, ncol,
        rel_embs + (size_t)l * 128, role_embs + (size_t)l * 64, col_embs + (size_t)l * 24,
        e1p + (size_t)l * 18 * 8192, e1b + (size_t)l * 256,
        e2p + (size_t)l * 8 * 8192,  e2b + (size_t)l * 256);
    node_kernel<<<(NN + 63) / 64, 256, 0, stream>>>(
        h, agg, nrole, ncol,
        role_embs + (size_t)l * 64, col_embs + (size_t)l * 24,
        n1p + (size_t)l * 17 * 8192, n1b + (size_t)l * 256,
        n2p + (size_t)l * 8 * 8192,  n2b + (size_t)l * 256,
        lng + (size_t)l * 256, lnb + (size_t)l * 256);
  }
  out_kernel<<<(NN + 63) / 64, 256, 0, stream>>>(h, outp, outb, (float*)d_out);
}

// Round 3
// 2015.849 us; speedup vs baseline: 1.3656x; 1.0233x over previous
//
#include <hip/hip_runtime.h>

#define NN 50000
#define NE 800000
#define H 256
#define NBINS 50176   // NN padded to 196*256

typedef __bf16 bf16x8 __attribute__((ext_vector_type(8)));
typedef __bf16 bf16x4 __attribute__((ext_vector_type(4)));
typedef float f32x4 __attribute__((ext_vector_type(4)));

static __device__ __forceinline__ f32x4 mfma16(bf16x8 a, bf16x8 b, f32x4 c) {
  return __builtin_amdgcn_mfma_f32_16x16x32_bf16(a, b, c, 0, 0, 0);
}
static __device__ __forceinline__ bf16x8 bzero8() {
  bf16x8 z;
#pragma unroll
  for (int j = 0; j < 8; ++j) z[j] = (__bf16)0.f;
  return z;
}
static __device__ __forceinline__ float silu_f(float v) {
  return v / (1.f + __expf(-v));
}

// ---------------------------------------------------------------------------
// Weight prep: fp32 -> bf16, K padded to mult of 32, layout [chunk][n][32k].
// ---------------------------------------------------------------------------
__global__ void prep_kernel(
    const float* __restrict__ e1w, const float* __restrict__ e2w,
    const float* __restrict__ n1w, const float* __restrict__ n2w,
    const float* __restrict__ outw,
    __bf16* __restrict__ e1p, __bf16* __restrict__ e2p,
    __bf16* __restrict__ n1p, __bf16* __restrict__ n2p,
    __bf16* __restrict__ outp)
{
  int i = blockIdx.x * 256 + threadIdx.x;
  if (i < 3 * 18 * 8192) {
    const int l = i / (18 * 8192), rem = i % (18 * 8192);
    const int c = rem >> 13, r2 = rem & 8191;
    const int n = r2 >> 5, k = c * 32 + (r2 & 31);
    e1p[i] = (k < 560) ? (__bf16)e1w[((size_t)l * 560 + k) * 256 + n] : (__bf16)0.f;
    return;
  }
  i -= 3 * 18 * 8192;
  if (i < 3 * 8 * 8192) {
    const int l = i / 65536, rem = i % 65536;
    const int c = rem >> 13, r2 = rem & 8191;
    const int n = r2 >> 5, k = c * 32 + (r2 & 31);
    e2p[i] = (__bf16)e2w[((size_t)l * 256 + k) * 256 + n];
    return;
  }
  i -= 3 * 8 * 8192;
  if (i < 3 * 17 * 8192) {
    const int l = i / (17 * 8192), rem = i % (17 * 8192);
    const int c = rem >> 13, r2 = rem & 8191;
    const int n = r2 >> 5, k = c * 32 + (r2 & 31);
    n1p[i] = (k < 528) ? (__bf16)n1w[((size_t)l * 528 + k) * 256 + n] : (__bf16)0.f;
    return;
  }
  i -= 3 * 17 * 8192;
  if (i < 3 * 8 * 8192) {
    const int l = i / 65536, rem = i % 65536;
    const int c = rem >> 13, r2 = rem & 8191;
    const int n = r2 >> 5, k = c * 32 + (r2 & 31);
    n2p[i] = (__bf16)n2w[((size_t)l * 256 + k) * 256 + n];
    return;
  }
  i -= 3 * 8 * 8192;
  if (i < 8 * 2048) {
    const int c = i >> 11, r2 = i & 2047;
    const int n = r2 >> 5, k = c * 32 + (r2 & 31);
    outp[i] = (__bf16)outw[(size_t)k * 64 + n];
  }
}

// ---------------------------------------------------------------------------
// Counting sort of edges by dst.
// ---------------------------------------------------------------------------
__global__ void hist_kernel(const int* __restrict__ dstI, int* __restrict__ cnt) {
  const int e = blockIdx.x * 256 + threadIdx.x;
  if (e < NE) atomicAdd(&cnt[dstI[e]], 1);
}

__global__ __launch_bounds__(256) void scan_kernel(int* __restrict__ cnt) {
  __shared__ int wsum[4];
  __shared__ int sCarry;
  const int tid = threadIdx.x, lane = tid & 63, wid = tid >> 6;
  if (tid == 0) sCarry = 0;
  __syncthreads();
  for (int base = 0; base < NBINS; base += 256) {
    const int i = base + tid;
    const int v = cnt[i];
    int x = v;
#pragma unroll
    for (int d = 1; d < 64; d <<= 1) {
      const int y = __shfl_up(x, d, 64);
      if (lane >= d) x += y;
    }
    if (lane == 63) wsum[wid] = x;
    __syncthreads();
    int wpref = 0;
#pragma unroll
    for (int w = 0; w < 4; ++w)
      if (w < wid) wpref += wsum[w];
    cnt[i] = sCarry + wpref + x - v;   // exclusive prefix
    __syncthreads();
    if (tid == 0) sCarry += wsum[0] + wsum[1] + wsum[2] + wsum[3];
    __syncthreads();
  }
}

__global__ void scatter_kernel(const int* __restrict__ srcI, const int* __restrict__ dstI,
                               const int* __restrict__ erel, int* __restrict__ cnt,
                               int* __restrict__ srcS, int* __restrict__ dstS,
                               int* __restrict__ relS) {
  const int e = blockIdx.x * 256 + threadIdx.x;
  if (e < NE) {
    const int d = dstI[e];
    const int pos = atomicAdd(&cnt[d], 1);
    srcS[pos] = srcI[e];
    dstS[pos] = d;
    relS[pos] = erel[e];
  }
}

// ---------------------------------------------------------------------------
// Input embedding.
// ---------------------------------------------------------------------------
__global__ __launch_bounds__(256) void embed_kernel(
    const float* __restrict__ scalars, const int* __restrict__ ncol,
    const int* __restrict__ nrole,
    const float* __restrict__ colEmb, const float* __restrict__ roleEmb,
    const float* __restrict__ inw, const float* __restrict__ inb,
    __bf16* __restrict__ h)
{
  __shared__ float sW[32][256];
  __shared__ float sIn[16][32];
  const int tid = threadIdx.x;
  const int n0 = blockIdx.x * 16;
#pragma unroll
  for (int j = 0; j < 32; ++j) sW[j][tid] = inw[j * 256 + tid];
  {
    const int node = tid >> 4, k = tid & 15;
    const int n = n0 + node;
    sIn[node][k] = (n < NN) ? scalars[(size_t)n * 16 + k] : 0.f;
  }
  if (tid < 16) {
    const int n = n0 + tid;
    if (n < NN) {
      const int c = ncol[n], r = nrole[n];
#pragma unroll
      for (int j = 0; j < 8; ++j) {
        sIn[tid][16 + j] = colEmb[c * 8 + j];
        sIn[tid][24 + j] = roleEmb[r * 8 + j];
      }
    } else {
#pragma unroll
      for (int j = 0; j < 16; ++j) sIn[tid][16 + j] = 0.f;
    }
  }
  __syncthreads();
  const float bias = inb[tid];
  for (int nn = 0; nn < 16; ++nn) {
    const int n = n0 + nn;
    if (n >= NN) break;
    float acc = bias;
#pragma unroll
    for (int k = 0; k < 32; ++k) acc += sIn[nn][k] * sW[k][tid];
    h[(size_t)n * H + tid] = (__bf16)acc;
  }
}

// ---------------------------------------------------------------------------
// Fused edge MLP + segmented scatter. Edges sorted by dst.
// LDS union: Ab (staging dbuf) / A2 (GEMM1 out, row-major) / A2t (GEMM2 out,
// col-major for vectorized segmented reduce). 4 blocks/CU.
// ---------------------------------------------------------------------------
__global__ __launch_bounds__(256, 4) void edge_kernel(
    const __bf16* __restrict__ h, float* __restrict__ agg,
    const int* __restrict__ srcS, const int* __restrict__ dstS,
    const int* __restrict__ relS, const int* __restrict__ nrole,
    const int* __restrict__ ncol,
    const float* __restrict__ relE, const float* __restrict__ roleE,
    const float* __restrict__ colE,
    const __bf16* __restrict__ e1p, const float* __restrict__ e1b,
    const __bf16* __restrict__ e2p, const float* __restrict__ e2b)
{
  __shared__ __align__(16) char uni[34816];
  __shared__ int sSrc[64], sDst[64];
  __shared__ __bf16 sRel[8][16], sRole[8][8], sCol[3][8];

  auto Ab  = (__bf16 (*)[64][72])uni;   // [2][64][72]  18.4 KB
  auto A2  = (__bf16 (*)[264])uni;      // [64][264]    33.8 KB
  auto A2t = (__bf16 (*)[68])uni;       // [256][68]    34.8 KB

  const int tid  = threadIdx.x;
  const int lane = tid & 63;
  const int wave = tid >> 6;
  const int l15  = lane & 15;
  const int quad = lane >> 4;
  const int e0   = blockIdx.x * 64;
  const int colW = wave * 64;

  if (tid < 64) { sSrc[tid] = srcS[e0 + tid]; sDst[tid] = dstS[e0 + tid]; }
  if (tid < 128) ((__bf16*)sRel)[tid] = (__bf16)relE[tid];
  else if (tid < 192) ((__bf16*)sRole)[tid - 128] = (__bf16)roleE[tid - 128];
  else if (tid < 216) ((__bf16*)sCol)[tid - 192] = (__bf16)colE[tid - 192];
  __syncthreads();

  // ---- embed fill into Ab[0] (K 512..575 -> chunks 16,17) ----
  {
    const int row = tid >> 2, q = tid & 3;
    __bf16* dp = &Ab[0][row][q * 16];
    if (q == 0) {
      const int r = relS[e0 + row];
#pragma unroll
      for (int j = 0; j < 16; ++j) dp[j] = sRel[r][j];
    } else if (q == 1) {
      const int rs = nrole[sSrc[row]], rd = nrole[sDst[row]];
#pragma unroll
      for (int j = 0; j < 8; ++j) { dp[j] = sRole[rs][j]; dp[8 + j] = sRole[rd][j]; }
    } else if (q == 2) {
      const int cs = ncol[sSrc[row]], cd = ncol[sDst[row]];
#pragma unroll
      for (int j = 0; j < 8; ++j) { dp[j] = sCol[cs][j]; dp[8 + j] = sCol[cd][j]; }
    } else {
#pragma unroll
      for (int j = 0; j < 16; ++j) dp[j] = (__bf16)0.f;
    }
  }

  const int rowA = tid >> 3;          // 0..31
  const int segO = (tid & 7) * 8;     // col offset in 64-wide slice
  bf16x8 rg0, rg1;
  auto issue = [&](int t) {
    const int* idx = (t < 4) ? sSrc : sDst;
    const int cb = (t & 3) * 64 + segO;
    rg0 = *(const bf16x8*)(h + (size_t)idx[rowA] * H + cb);
    rg1 = *(const bf16x8*)(h + (size_t)idx[rowA + 32] * H + cb);
  };

  f32x4 acc[4][4] = {};
  auto compute2 = [&](const __bf16 (*Abuf)[72], int c0) {
#pragma unroll
    for (int cc = 0; cc < 2; ++cc) {
      const int c = c0 + cc;
      bf16x8 bfr[4], afr[4];
#pragma unroll
      for (int nj = 0; nj < 4; ++nj)
        bfr[nj] = *(const bf16x8*)(e1p + ((size_t)c * 256 + colW + nj * 16 + l15) * 32 + quad * 8);
#pragma unroll
      for (int mi = 0; mi < 4; ++mi)
        afr[mi] = *(const bf16x8*)&Abuf[mi * 16 + l15][cc * 32 + quad * 8];
#pragma unroll
      for (int mi = 0; mi < 4; ++mi)
#pragma unroll
        for (int nj = 0; nj < 4; ++nj)
          acc[mi][nj] = mfma16(afr[mi], bfr[nj], acc[mi][nj]);
    }
  };

  issue(0);              // stage-0 gathers in flight during embed compute
  __syncthreads();       // Ab[0] (embeds) ready
  compute2(Ab[0], 16);   // chunks 16,17
  *(bf16x8*)&Ab[1][rowA][segO] = rg0;
  *(bf16x8*)&Ab[1][rowA + 32][segO] = rg1;
  __syncthreads();       // Ab[1] (stage 0) ready

  for (int t = 0; t < 8; ++t) {
    if (t < 7) issue(t + 1);
    compute2(Ab[(t + 1) & 1], 2 * t);
    if (t < 7) {
      const int b = t & 1;
      *(bf16x8*)&Ab[b][rowA][segO] = rg0;
      *(bf16x8*)&Ab[b][rowA + 32][segO] = rg1;
      __syncthreads();
    }
  }
  __syncthreads();   // all Ab reads done before A2 (aliased) is written

  // ---- epilogue GEMM1: silu -> A2 (bf16, row-major) ----
  float b1[4];
#pragma unroll
  for (int nj = 0; nj < 4; ++nj) b1[nj] = e1b[colW + nj * 16 + l15];
#pragma unroll
  for (int mi = 0; mi < 4; ++mi)
#pragma unroll
    for (int nj = 0; nj < 4; ++nj)
#pragma unroll
      for (int r = 0; r < 4; ++r)
        A2[mi * 16 + quad * 4 + r][colW + nj * 16 + l15] =
            (__bf16)silu_f(acc[mi][nj][r] + b1[nj]);
  __syncthreads();

  // ---- GEMM2 ----
  f32x4 acc2[4][4] = {};
#pragma unroll
  for (int c = 0; c < 8; ++c) {
    bf16x8 bfr[4], afr[4];
#pragma unroll
    for (int nj = 0; nj < 4; ++nj)
      bfr[nj] = *(const bf16x8*)(e2p + ((size_t)c * 256 + colW + nj * 16 + l15) * 32 + quad * 8);
#pragma unroll
    for (int mi = 0; mi < 4; ++mi)
      afr[mi] = *(const bf16x8*)&A2[mi * 16 + l15][c * 32 + quad * 8];
#pragma unroll
    for (int mi = 0; mi < 4; ++mi)
#pragma unroll
      for (int nj = 0; nj < 4; ++nj)
        acc2[mi][nj] = mfma16(afr[mi], bfr[nj], acc2[mi][nj]);
  }

  float b2[4];
#pragma unroll
  for (int nj = 0; nj < 4; ++nj) b2[nj] = e2b[colW + nj * 16 + l15];
  __syncthreads();   // A2 reads done before A2t (aliased) is written

  // ---- write m transposed: A2t[col][row], packed b64 stores ----
#pragma unroll
  for (int mi = 0; mi < 4; ++mi)
#pragma unroll
    for (int nj = 0; nj < 4; ++nj) {
      const int col = colW + nj * 16 + l15;
      bf16x4 pv;
#pragma unroll
      for (int r = 0; r < 4; ++r)
        pv[r] = (__bf16)silu_f(acc2[mi][nj][r] + b2[nj]);
      *(bf16x4*)&A2t[col][mi * 16 + quad * 4] = pv;
    }
  __syncthreads();

  // ---- vectorized segmented reduce: thread = column ----
  {
    const int col = tid;
    const bool f = (lane > 0) && (sDst[lane] != sDst[lane - 1]);
    const unsigned long long mask = __ballot(f);
    bf16x4 v[16];
#pragma unroll
    for (int j = 0; j < 16; ++j) v[j] = *(const bf16x4*)&A2t[col][j * 4];
    float sum = 0.f;
#pragma unroll
    for (int r = 0; r < 64; ++r) {
      sum += (float)v[r >> 2][r & 3];
      if (r == 63 || ((mask >> (r + 1)) & 1ull)) {
        const int d = sDst[r];
        atomicAdd(agg + (size_t)d * H + col, sum);
        sum = 0.f;
      }
    }
  }
}

// ---------------------------------------------------------------------------
// Fused node update. LDS union Abuf/A2 -> 4 blocks/CU.
// ---------------------------------------------------------------------------
__global__ __launch_bounds__(256, 4) void node_kernel(
    __bf16* __restrict__ h, const float* __restrict__ agg,
    const int* __restrict__ nrole, const int* __restrict__ ncol,
    const float* __restrict__ roleE, const float* __restrict__ colE,
    const __bf16* __restrict__ n1p, const float* __restrict__ n1b,
    const __bf16* __restrict__ n2p, const float* __restrict__ n2b,
    const float* __restrict__ lng, const float* __restrict__ lnb)
{
  __shared__ __align__(16) char uni[33792];
  __shared__ __bf16 sRole[8][8], sCol[3][8];
  __shared__ float sSum[64][4], sSsq[64][4];

  auto Abuf = (__bf16 (*)[72])uni;   // [64][72]
  auto A2   = (__bf16 (*)[264])uni;  // [64][264]

  const int tid  = threadIdx.x;
  const int lane = tid & 63;
  const int wave = tid >> 6;
  const int l15  = lane & 15;
  const int quad = lane >> 4;
  const int n0   = blockIdx.x * 64;
  const int colW = wave * 64;

  if (tid < 64) ((__bf16*)sRole)[tid] = (__bf16)roleE[tid];
  else if (tid < 88) ((__bf16*)sCol)[tid - 64] = (__bf16)colE[tid - 64];
  __syncthreads();

  f32x4 acc[4][4] = {};
  for (int s = 0; s < 9; ++s) {
    if (s) __syncthreads();
    if (s < 4) {
#pragma unroll
      for (int it = 0; it < 2; ++it) {
        const int t = tid + it * 256;
        const int row = t >> 3, seg = t & 7;
        const int n = n0 + row;
        bf16x8 v = bzero8();
        if (n < NN) v = *(const bf16x8*)(h + (size_t)n * H + s * 64 + seg * 8);
        *(bf16x8*)&Abuf[row][seg * 8] = v;
      }
    } else if (s < 8) {
#pragma unroll
      for (int it = 0; it < 2; ++it) {
        const int t = tid + it * 256;
        const int row = t >> 3, seg = t & 7;
        const int n = n0 + row;
        bf16x8 v = bzero8();
        if (n < NN) {
          const float* p = agg + (size_t)n * H + (s - 4) * 64 + seg * 8;
          const float4 u0 = *(const float4*)p;
          const float4 u1 = *(const float4*)(p + 4);
          v[0] = (__bf16)u0.x; v[1] = (__bf16)u0.y; v[2] = (__bf16)u0.z; v[3] = (__bf16)u0.w;
          v[4] = (__bf16)u1.x; v[5] = (__bf16)u1.y; v[6] = (__bf16)u1.z; v[7] = (__bf16)u1.w;
        }
        *(bf16x8*)&Abuf[row][seg * 8] = v;
      }
    } else {
      const int row = tid >> 2, q = tid & 3;
      const int n = n0 + row;
      __bf16* dp = &Abuf[row][q * 16];
      if (q == 0 && n < NN) {
        const int r = nrole[n], c = ncol[n];
#pragma unroll
        for (int j = 0; j < 8; ++j) { dp[j] = sRole[r][j]; dp[8 + j] = sCol[c][j]; }
      } else {
#pragma unroll
        for (int j = 0; j < 16; ++j) dp[j] = (__bf16)0.f;
      }
    }
    __syncthreads();
#pragma unroll
    for (int cc = 0; cc < 2; ++cc) {
      const int c = 2 * s + cc;
      if (c >= 17) break;
      bf16x8 bfr[4], afr[4];
#pragma unroll
      for (int nj = 0; nj < 4; ++nj)
        bfr[nj] = *(const bf16x8*)(n1p + ((size_t)c * 256 + colW + nj * 16 + l15) * 32 + quad * 8);
#pragma unroll
      for (int mi = 0; mi < 4; ++mi)
        afr[mi] = *(const bf16x8*)&Abuf[mi * 16 + l15][cc * 32 + quad * 8];
#pragma unroll
      for (int mi = 0; mi < 4; ++mi)
#pragma unroll
        for (int nj = 0; nj < 4; ++nj)
          acc[mi][nj] = mfma16(afr[mi], bfr[nj], acc[mi][nj]);
    }
  }
  __syncthreads();   // Abuf reads done before A2 (aliased) is written

  float b1[4];
#pragma unroll
  for (int nj = 0; nj < 4; ++nj) b1[nj] = n1b[colW + nj * 16 + l15];
#pragma unroll
  for (int mi = 0; mi < 4; ++mi)
#pragma unroll
    for (int nj = 0; nj < 4; ++nj)
#pragma unroll
      for (int r = 0; r < 4; ++r)
        A2[mi * 16 + quad * 4 + r][colW + nj * 16 + l15] =
            (__bf16)silu_f(acc[mi][nj][r] + b1[nj]);
  __syncthreads();

  f32x4 acc2[4][4] = {};
#pragma unroll
  for (int c = 0; c < 8; ++c) {
    bf16x8 bfr[4], afr[4];
#pragma unroll
    for (int nj = 0; nj < 4; ++nj)
      bfr[nj] = *(const bf16x8*)(n2p + ((size_t)c * 256 + colW + nj * 16 + l15) * 32 + quad * 8);
#pragma unroll
    for (int mi = 0; mi < 4; ++mi)
      afr[mi] = *(const bf16x8*)&A2[mi * 16 + l15][c * 32 + quad * 8];
#pragma unroll
    for (int mi = 0; mi < 4; ++mi)
#pragma unroll
      for (int nj = 0; nj < 4; ++nj)
        acc2[mi][nj] = mfma16(afr[mi], bfr[nj], acc2[mi][nj]);
  }

  float b2[4], g4[4], bb4[4];
#pragma unroll
  for (int nj = 0; nj < 4; ++nj) {
    const int col = colW + nj * 16 + l15;
    b2[nj] = n2b[col]; g4[nj] = lng[col]; bb4[nj] = lnb[col];
  }
#pragma unroll
  for (int mi = 0; mi < 4; ++mi)
#pragma unroll
    for (int r = 0; r < 4; ++r) {
      const int n = n0 + mi * 16 + quad * 4 + r;
#pragma unroll
      for (int nj = 0; nj < 4; ++nj) {
        const float hv = (n < NN) ? (float)h[(size_t)n * H + colW + nj * 16 + l15] : 0.f;
        acc2[mi][nj][r] += b2[nj] + hv;
      }
    }
#pragma unroll
  for (int mi = 0; mi < 4; ++mi)
#pragma unroll
    for (int r = 0; r < 4; ++r) {
      float s1 = 0.f, s2 = 0.f;
#pragma unroll
      for (int nj = 0; nj < 4; ++nj) {
        const float v = acc2[mi][nj][r];
        s1 += v; s2 += v * v;
      }
#pragma unroll
      for (int d = 1; d < 16; d <<= 1) {
        s1 += __shfl_xor(s1, d, 16);
        s2 += __shfl_xor(s2, d, 16);
      }
      if (l15 == 0) {
        const int row = mi * 16 + quad * 4 + r;
        sSum[row][wave] = s1; sSsq[row][wave] = s2;
      }
    }
  __syncthreads();
#pragma unroll
  for (int mi = 0; mi < 4; ++mi)
#pragma unroll
    for (int r = 0; r < 4; ++r) {
      const int row = mi * 16 + quad * 4 + r;
      const int n = n0 + row;
      const float t1 = sSum[row][0] + sSum[row][1] + sSum[row][2] + sSum[row][3];
      const float t2 = sSsq[row][0] + sSsq[row][1] + sSsq[row][2] + sSsq[row][3];
      const float mu = t1 * (1.f / 256.f);
      float var = t2 * (1.f / 256.f) - mu * mu;
      var = var < 0.f ? 0.f : var;
      const float rstd = rsqrtf(var + 1e-5f);
      if (n < NN) {
#pragma unroll
        for (int nj = 0; nj < 4; ++nj) {
          const float o = g4[nj] * (acc2[mi][nj][r] - mu) * rstd + bb4[nj];
          h[(size_t)n * H + colW + nj * 16 + l15] = (__bf16)o;
        }
      }
    }
}

// ---------------------------------------------------------------------------
// Output projection.
// ---------------------------------------------------------------------------
__global__ __launch_bounds__(256) void out_kernel(
    const __bf16* __restrict__ h, const __bf16* __restrict__ outp,
    const float* __restrict__ outb, float* __restrict__ out)
{
  const int tid  = threadIdx.x;
  const int lane = tid & 63;
  const int wave = tid >> 6;
  const int l15  = lane & 15;
  const int quad = lane >> 4;
  const int m0   = blockIdx.x * 64 + wave * 16;
  int ar = m0 + l15;
  if (ar >= NN) ar = NN - 1;
  f32x4 acc[4] = {};
#pragma unroll
  for (int c = 0; c < 8; ++c) {
    const bf16x8 a = *(const bf16x8*)(h + (size_t)ar * H + c * 32 + quad * 8);
#pragma unroll
    for (int nj = 0; nj < 4; ++nj) {
      const bf16x8 b = *(const bf16x8*)(outp + ((size_t)c * 64 + nj * 16 + l15) * 32 + quad * 8);
      acc[nj] = mfma16(a, b, acc[nj]);
    }
  }
#pragma unroll
  for (int nj = 0; nj < 4; ++nj) {
    const float bb = outb[nj * 16 + l15];
#pragma unroll
    for (int r = 0; r < 4; ++r) {
      const int row = m0 + quad * 4 + r;
      if (row < NN) out[(size_t)row * 64 + nj * 16 + l15] = acc[nj][r] + bb;
    }
  }
}

// ---------------------------------------------------------------------------
extern "C" void kernel_launch(void* const* d_in, const int* in_sizes, int n_in,
                              void* d_out, int out_size, void* d_ws, size_t ws_size,
                              hipStream_t stream) {
  const float* scalars   = (const float*)d_in[0];
  const int*   ei        = (const int*)d_in[1];
  const int*   erel      = (const int*)d_in[2];
  const int*   ncol      = (const int*)d_in[3];
  const int*   nrole     = (const int*)d_in[4];
  const float* blk_role  = (const float*)d_in[5];
  const float* blk_col   = (const float*)d_in[6];
  const float* inw       = (const float*)d_in[7];
  const float* inb       = (const float*)d_in[8];
  const float* rel_embs  = (const float*)d_in[9];
  const float* role_embs = (const float*)d_in[10];
  const float* col_embs  = (const float*)d_in[11];
  const float* e1w       = (const float*)d_in[12];
  const float* e1b       = (const float*)d_in[13];
  const float* e2w       = (const float*)d_in[14];
  const float* e2b       = (const float*)d_in[15];
  const float* n1w       = (const float*)d_in[16];
  const float* n1b       = (const float*)d_in[17];
  const float* n2w       = (const float*)d_in[18];
  const float* n2b       = (const float*)d_in[19];
  const float* lng       = (const float*)d_in[20];
  const float* lnb       = (const float*)d_in[21];
  const float* outw      = (const float*)d_in[22];
  const float* outb      = (const float*)d_in[23];

  const int* srcI = ei;
  const int* dstI = ei + NE;

  char* ws = (char*)d_ws;
  size_t off = 0;
  auto take = [&](size_t bytes) -> char* {
    off = (off + 255) & ~(size_t)255;
    char* p = ws + off;
    off += bytes;
    return p;
  };
  __bf16* h    = (__bf16*)take((size_t)NN * H * 2);
  float*  agg  = (float*)take((size_t)NN * H * 4);
  __bf16* e1p  = (__bf16*)take((size_t)3 * 18 * 8192 * 2);
  __bf16* e2p  = (__bf16*)take((size_t)3 * 8 * 8192 * 2);
  __bf16* n1p  = (__bf16*)take((size_t)3 * 17 * 8192 * 2);
  __bf16* n2p  = (__bf16*)take((size_t)3 * 8 * 8192 * 2);
  __bf16* outp = (__bf16*)take((size_t)8 * 2048 * 2);
  int*    cnt  = (int*)take((size_t)NBINS * 4);
  int*    srcS = (int*)take((size_t)NE * 4);
  int*    dstS = (int*)take((size_t)NE * 4);
  int*    relS = (int*)take((size_t)NE * 4);

  prep_kernel<<<4960, 256, 0, stream>>>(e1w, e2w, n1w, n2w, outw,
                                        e1p, e2p, n1p, n2p, outp);
  embed_kernel<<<(NN + 15) / 16, 256, 0, stream>>>(scalars, ncol, nrole,
                                                   blk_col, blk_role, inw, inb, h);
  // counting sort of edges by dst
  hipMemsetAsync(cnt, 0, (size_t)NBINS * 4, stream);
  hist_kernel<<<(NE + 255) / 256, 256, 0, stream>>>(dstI, cnt);
  scan_kernel<<<1, 256, 0, stream>>>(cnt);
  scatter_kernel<<<(NE + 255) / 256, 256, 0, stream>>>(srcI, dstI, erel, cnt,
                                                       srcS, dstS, relS);

  for (int l = 0; l < 3; ++l) {
    hipMemsetAsync(agg, 0, (size_t)NN * H * 4, stream);
    edge_kernel<<<NE / 64, 256, 0, stream>>>(
        h, agg, srcS, dstS, relS, nrole, ncol,
        rel_embs + (size_t)l * 128, role_embs + (size_t)l * 64, col_embs + (size_t)l * 24,
        e1p + (size_t)l * 18 * 8192, e1b + (size_t)l * 256,
        e2p + (size_t)l * 8 * 8192,  e2b + (size_t)l * 256);
    node_kernel<<<(NN + 63) / 64, 256, 0, stream>>>(
        h, agg, nrole, ncol,
        role_embs + (size_t)l * 64, col_embs + (size_t)l * 24,
        n1p + (size_t)l * 17 * 8192, n1b + (size_t)l * 256,
        n2p + (size_t)l * 8 * 8192,  n2b + (size_t)l * 256,
        lng + (size_t)l * 256, lnb + (size_t)l * 256);
  }
  out_kernel<<<(NN + 63) / 64, 256, 0, stream>>>(h, outp, outb, (float*)d_out);
}

// Round 4
// 1296.631 us; speedup vs baseline: 2.1231x; 1.5547x over previous
//
#include <hip/hip_runtime.h>

#define NN 50000
#define NE 800000
#define H 256
#define NBINS 50176   // NN padded to 196*256

typedef __bf16 bf16x8 __attribute__((ext_vector_type(8)));
typedef __bf16 bf16x4 __attribute__((ext_vector_type(4)));
typedef float f32x4 __attribute__((ext_vector_type(4)));

static __device__ __forceinline__ f32x4 mfma16(bf16x8 a, bf16x8 b, f32x4 c) {
  return __builtin_amdgcn_mfma_f32_16x16x32_bf16(a, b, c, 0, 0, 0);
}
static __device__ __forceinline__ bf16x8 bzero8() {
  bf16x8 z;
#pragma unroll
  for (int j = 0; j < 8; ++j) z[j] = (__bf16)0.f;
  return z;
}
// division-free silu: x * rcp(1 + 2^(-x*log2e)); ~1ulp rcp/exp, fine for bf16 out
static __device__ __forceinline__ float silu_f(float v) {
  return v * __builtin_amdgcn_rcpf(1.f + __builtin_amdgcn_exp2f(v * -1.442695041f));
}

// ---------------------------------------------------------------------------
// Weight prep: fp32 -> bf16, layout [chunk][n][32k] (B fragment = 16B load).
// wsd: [3][8][512][32]   Ws|Wd halves of e1w rows 0..511
// e2p: [3][8][256][32]
// n1p: [3][17][256][32]  (K 528->544 zero pad)
// n2p: [3][8][256][32]
// outp: [8][64][32]
// ---------------------------------------------------------------------------
__global__ void prep_kernel(
    const float* __restrict__ e1w, const float* __restrict__ e2w,
    const float* __restrict__ n1w, const float* __restrict__ n2w,
    const float* __restrict__ outw,
    __bf16* __restrict__ wsd, __bf16* __restrict__ e2p,
    __bf16* __restrict__ n1p, __bf16* __restrict__ n2p,
    __bf16* __restrict__ outp)
{
  int i = blockIdx.x * 256 + threadIdx.x;
  if (i < 3 * 131072) {
    const int l = i / 131072, rem = i % 131072;
    const int c = rem >> 14, r2 = rem & 16383;
    const int n = r2 >> 5, k = c * 32 + (r2 & 31);
    wsd[i] = (n < 256) ? (__bf16)e1w[((size_t)l * 560 + k) * 256 + n]
                       : (__bf16)e1w[((size_t)l * 560 + 256 + k) * 256 + (n - 256)];
    return;
  }
  i -= 3 * 131072;
  if (i < 3 * 8 * 8192) {
    const int l = i / 65536, rem = i % 65536;
    const int c = rem >> 13, r2 = rem & 8191;
    const int n = r2 >> 5, k = c * 32 + (r2 & 31);
    e2p[i] = (__bf16)e2w[((size_t)l * 256 + k) * 256 + n];
    return;
  }
  i -= 3 * 8 * 8192;
  if (i < 3 * 17 * 8192) {
    const int l = i / (17 * 8192), rem = i % (17 * 8192);
    const int c = rem >> 13, r2 = rem & 8191;
    const int n = r2 >> 5, k = c * 32 + (r2 & 31);
    n1p[i] = (k < 528) ? (__bf16)n1w[((size_t)l * 528 + k) * 256 + n] : (__bf16)0.f;
    return;
  }
  i -= 3 * 17 * 8192;
  if (i < 3 * 8 * 8192) {
    const int l = i / 65536, rem = i % 65536;
    const int c = rem >> 13, r2 = rem & 8191;
    const int n = r2 >> 5, k = c * 32 + (r2 & 31);
    n2p[i] = (__bf16)n2w[((size_t)l * 256 + k) * 256 + n];
    return;
  }
  i -= 3 * 8 * 8192;
  if (i < 8 * 2048) {
    const int c = i >> 11, r2 = i & 2047;
    const int n = r2 >> 5, k = c * 32 + (r2 & 31);
    outp[i] = (__bf16)outw[(size_t)k * 64 + n];
  }
}

// ---------------------------------------------------------------------------
// Embed-weight tables (f32), one block per layer:
//   TR[l][8][256]  = rel_e @ e1w[512:528]
//   TS[l][24][256] = role_e@e1w[528:536] + col_e@e1w[544:552]   (idx ro*3+co)
//   TD[l][24][256] = role_e@e1w[536:544] + col_e@e1w[552:560] + e1b
// ---------------------------------------------------------------------------
__global__ __launch_bounds__(256) void tbl_kernel(
    const float* __restrict__ e1w, const float* __restrict__ e1b,
    const float* __restrict__ rel_embs, const float* __restrict__ role_embs,
    const float* __restrict__ col_embs,
    float* __restrict__ TR, float* __restrict__ TS, float* __restrict__ TD)
{
  const int l = blockIdx.x, c = threadIdx.x;
  float w[48];
#pragma unroll
  for (int j = 0; j < 48; ++j) w[j] = e1w[((size_t)l * 560 + 512 + j) * 256 + c];
#pragma unroll
  for (int r = 0; r < 8; ++r) {
    float s = 0.f;
#pragma unroll
    for (int j = 0; j < 16; ++j) s += rel_embs[l * 128 + r * 16 + j] * w[j];
    TR[((size_t)l * 8 + r) * 256 + c] = s;
  }
  const float bias = e1b[l * 256 + c];
#pragma unroll
  for (int ro = 0; ro < 8; ++ro) {
    float ss = 0.f, sd = 0.f;
#pragma unroll
    for (int j = 0; j < 8; ++j) {
      ss += role_embs[l * 64 + ro * 8 + j] * w[16 + j];
      sd += role_embs[l * 64 + ro * 8 + j] * w[24 + j];
    }
#pragma unroll
    for (int co = 0; co < 3; ++co) {
      float cs = 0.f, cd = 0.f;
#pragma unroll
      for (int j = 0; j < 8; ++j) {
        cs += col_embs[l * 24 + co * 8 + j] * w[32 + j];
        cd += col_embs[l * 24 + co * 8 + j] * w[40 + j];
      }
      TS[((size_t)l * 24 + ro * 3 + co) * 256 + c] = ss + cs;
      TD[((size_t)l * 24 + ro * 3 + co) * 256 + c] = sd + cd + bias;
    }
  }
}

// ---------------------------------------------------------------------------
// Counting sort of edges by dst.
// ---------------------------------------------------------------------------
__global__ void hist_kernel(const int* __restrict__ dstI, int* __restrict__ cnt) {
  const int e = blockIdx.x * 256 + threadIdx.x;
  if (e < NE) atomicAdd(&cnt[dstI[e]], 1);
}

__global__ __launch_bounds__(256) void scan_kernel(int* __restrict__ cnt) {
  __shared__ int wsum[4];
  __shared__ int sCarry;
  const int tid = threadIdx.x, lane = tid & 63, wid = tid >> 6;
  if (tid == 0) sCarry = 0;
  __syncthreads();
  for (int base = 0; base < NBINS; base += 256) {
    const int i = base + tid;
    const int v = cnt[i];
    int x = v;
#pragma unroll
    for (int d = 1; d < 64; d <<= 1) {
      const int y = __shfl_up(x, d, 64);
      if (lane >= d) x += y;
    }
    if (lane == 63) wsum[wid] = x;
    __syncthreads();
    int wpref = 0;
#pragma unroll
    for (int w = 0; w < 4; ++w)
      if (w < wid) wpref += wsum[w];
    cnt[i] = sCarry + wpref + x - v;   // exclusive prefix
    __syncthreads();
    if (tid == 0) sCarry += wsum[0] + wsum[1] + wsum[2] + wsum[3];
    __syncthreads();
  }
}

__global__ void scatter_kernel(const int* __restrict__ srcI, const int* __restrict__ dstI,
                               const int* __restrict__ erel, int* __restrict__ cnt,
                               int* __restrict__ srcS, int* __restrict__ dstS,
                               int* __restrict__ relS) {
  const int e = blockIdx.x * 256 + threadIdx.x;
  if (e < NE) {
    const int d = dstI[e];
    const int pos = atomicAdd(&cnt[d], 1);
    srcS[pos] = srcI[e];
    dstS[pos] = d;
    relS[pos] = erel[e];
  }
}

// ---------------------------------------------------------------------------
// Input embedding.
// ---------------------------------------------------------------------------
__global__ __launch_bounds__(256) void embed_kernel(
    const float* __restrict__ scalars, const int* __restrict__ ncol,
    const int* __restrict__ nrole,
    const float* __restrict__ colEmb, const float* __restrict__ roleEmb,
    const float* __restrict__ inw, const float* __restrict__ inb,
    __bf16* __restrict__ h)
{
  __shared__ float sW[32][256];
  __shared__ float sIn[16][32];
  const int tid = threadIdx.x;
  const int n0 = blockIdx.x * 16;
#pragma unroll
  for (int j = 0; j < 32; ++j) sW[j][tid] = inw[j * 256 + tid];
  {
    const int node = tid >> 4, k = tid & 15;
    const int n = n0 + node;
    sIn[node][k] = (n < NN) ? scalars[(size_t)n * 16 + k] : 0.f;
  }
  if (tid < 16) {
    const int n = n0 + tid;
    if (n < NN) {
      const int c = ncol[n], r = nrole[n];
#pragma unroll
      for (int j = 0; j < 8; ++j) {
        sIn[tid][16 + j] = colEmb[c * 8 + j];
        sIn[tid][24 + j] = roleEmb[r * 8 + j];
      }
    } else {
#pragma unroll
      for (int j = 0; j < 16; ++j) sIn[tid][16 + j] = 0.f;
    }
  }
  __syncthreads();
  const float bias = inb[tid];
  for (int nn = 0; nn < 16; ++nn) {
    const int n = n0 + nn;
    if (n >= NN) break;
    float acc = bias;
#pragma unroll
    for (int k = 0; k < 32; ++k) acc += sIn[nn][k] * sW[k][tid];
    h[(size_t)n * H + tid] = (__bf16)acc;
  }
}

// ---------------------------------------------------------------------------
// Node projections for edge MLP layer 1:
//   PS[n] = h[n]@Ws + TS[role,col] ;  PD[n] = h[n]@Wd + TD[role,col] (b1 in TD)
// blockIdx: (node_group, half). 64 nodes x 256 cols, 4 waves x 64 cols.
// ---------------------------------------------------------------------------
__global__ __launch_bounds__(256, 4) void pre_kernel(
    const __bf16* __restrict__ h, const int* __restrict__ nrole,
    const int* __restrict__ ncol, const __bf16* __restrict__ wsd,
    const float* __restrict__ TS, const float* __restrict__ TD,
    __bf16* __restrict__ PS, __bf16* __restrict__ PD)
{
  __shared__ __align__(16) __bf16 Ah[64][72];
  const int tid  = threadIdx.x;
  const int lane = tid & 63;
  const int wave = tid >> 6;
  const int l15  = lane & 15;
  const int quad = lane >> 4;
  const int n0   = (blockIdx.x >> 1) * 64;
  const int half = blockIdx.x & 1;
  const int colW = wave * 64;

  f32x4 acc[4][4] = {};
  for (int s = 0; s < 4; ++s) {
    if (s) __syncthreads();
#pragma unroll
    for (int it = 0; it < 2; ++it) {
      const int t = tid + it * 256;
      const int row = t >> 3, seg = t & 7;
      const int n = n0 + row;
      bf16x8 v = bzero8();
      if (n < NN) v = *(const bf16x8*)(h + (size_t)n * H + s * 64 + seg * 8);
      *(bf16x8*)&Ah[row][seg * 8] = v;
    }
    __syncthreads();
#pragma unroll
    for (int cc = 0; cc < 2; ++cc) {
      const int c = 2 * s + cc;
      bf16x8 bfr[4], afr[4];
#pragma unroll
      for (int nj = 0; nj < 4; ++nj)
        bfr[nj] = *(const bf16x8*)(wsd + ((size_t)c * 512 + half * 256 + colW + nj * 16 + l15) * 32 + quad * 8);
#pragma unroll
      for (int mi = 0; mi < 4; ++mi)
        afr[mi] = *(const bf16x8*)&Ah[mi * 16 + l15][cc * 32 + quad * 8];
#pragma unroll
      for (int mi = 0; mi < 4; ++mi)
#pragma unroll
        for (int nj = 0; nj < 4; ++nj)
          acc[mi][nj] = mfma16(afr[mi], bfr[nj], acc[mi][nj]);
    }
  }

  const float* T = half ? TD : TS;
  __bf16* P = half ? PD : PS;
#pragma unroll
  for (int mi = 0; mi < 4; ++mi)
#pragma unroll
    for (int r = 0; r < 4; ++r) {
      const int n = n0 + mi * 16 + quad * 4 + r;
      if (n < NN) {
        const int ti = (nrole[n] * 3 + ncol[n]) * 256;
#pragma unroll
        for (int nj = 0; nj < 4; ++nj) {
          const int col = colW + nj * 16 + l15;
          P[(size_t)n * H + col] = (__bf16)(acc[mi][nj][r] + T[ti + col]);
        }
      }
    }
}

// ---------------------------------------------------------------------------
// Fused edge MLP + segmented scatter (edges sorted by dst):
//   m1 = silu(PS[src] + PD[dst] + TR[rel])   (no GEMM1!)
//   m2 = silu(m1 @ e2w + e2b)
//   segment-reduce by dst; interior segments -> plain store, boundary -> atomic
// ---------------------------------------------------------------------------
__global__ __launch_bounds__(256, 4) void edge_kernel(
    const __bf16* __restrict__ PS, const __bf16* __restrict__ PD,
    float* __restrict__ agg,
    const int* __restrict__ srcS, const int* __restrict__ dstS,
    const int* __restrict__ relS, const float* __restrict__ TR,
    const __bf16* __restrict__ e2p, const float* __restrict__ e2b)
{
  __shared__ __align__(16) char uni[34816];
  __shared__ __bf16 sTrel[8][256];
  __shared__ int sSrc[64], sDst[64], sRel[64];
  __shared__ int sFlag[2];

  auto A2  = (__bf16 (*)[264])uni;      // [64][264]  m1 row-major
  auto A2t = (__bf16 (*)[68])uni;       // [256][68]  m2 col-major (aliased)

  const int tid  = threadIdx.x;
  const int lane = tid & 63;
  const int wave = tid >> 6;
  const int l15  = lane & 15;
  const int quad = lane >> 4;
  const int e0   = blockIdx.x * 64;
  const int colW = wave * 64;

  if (tid < 64) {
    sSrc[tid] = srcS[e0 + tid];
    sDst[tid] = dstS[e0 + tid];
    sRel[tid] = relS[e0 + tid];
  }
  {
    const int r = tid >> 5, cs = (tid & 31) * 8;
    const float* p = TR + r * 256 + cs;
    bf16x8 v;
#pragma unroll
    for (int j = 0; j < 8; ++j) v[j] = (__bf16)p[j];
    *(bf16x8*)&sTrel[r][cs] = v;
  }
  if (tid == 0) sFlag[0] = (e0 > 0) && (dstS[e0 - 1] == dstS[e0]);
  if (tid == 1) sFlag[1] = (e0 + 64 < NE) && (dstS[e0 + 64] == dstS[e0 + 63]);
  __syncthreads();

  // ---- build m1 directly into A2 ----
  {
    const int brow = tid >> 5;          // 0..7
    const int cs = (tid & 31) * 8;
#pragma unroll
    for (int it = 0; it < 8; ++it) {
      const int row = it * 8 + brow;
      const bf16x8 a = *(const bf16x8*)(PS + (size_t)sSrc[row] * H + cs);
      const bf16x8 b = *(const bf16x8*)(PD + (size_t)sDst[row] * H + cs);
      const bf16x8 t = *(const bf16x8*)&sTrel[sRel[row]][cs];
      bf16x8 o;
#pragma unroll
      for (int j = 0; j < 8; ++j)
        o[j] = (__bf16)silu_f((float)a[j] + (float)b[j] + (float)t[j]);
      *(bf16x8*)&A2[row][cs] = o;
    }
  }
  __syncthreads();

  // ---- GEMM2 ----
  f32x4 acc2[4][4] = {};
#pragma unroll
  for (int c = 0; c < 8; ++c) {
    bf16x8 bfr[4], afr[4];
#pragma unroll
    for (int nj = 0; nj < 4; ++nj)
      bfr[nj] = *(const bf16x8*)(e2p + ((size_t)c * 256 + colW + nj * 16 + l15) * 32 + quad * 8);
#pragma unroll
    for (int mi = 0; mi < 4; ++mi)
      afr[mi] = *(const bf16x8*)&A2[mi * 16 + l15][c * 32 + quad * 8];
#pragma unroll
    for (int mi = 0; mi < 4; ++mi)
#pragma unroll
      for (int nj = 0; nj < 4; ++nj)
        acc2[mi][nj] = mfma16(afr[mi], bfr[nj], acc2[mi][nj]);
  }

  float b2[4];
#pragma unroll
  for (int nj = 0; nj < 4; ++nj) b2[nj] = e2b[colW + nj * 16 + l15];
  __syncthreads();   // A2 reads done before A2t (aliased) write

  // ---- write m2 transposed: A2t[col][row] ----
#pragma unroll
  for (int mi = 0; mi < 4; ++mi)
#pragma unroll
    for (int nj = 0; nj < 4; ++nj) {
      const int col = colW + nj * 16 + l15;
      bf16x4 pv;
#pragma unroll
      for (int r = 0; r < 4; ++r)
        pv[r] = (__bf16)silu_f(acc2[mi][nj][r] + b2[nj]);
      *(bf16x4*)&A2t[col][mi * 16 + quad * 4] = pv;
    }
  __syncthreads();

  // ---- segmented reduce: thread = column; interior segs = plain store ----
  {
    const int col = tid;
    const bool f = (lane > 0) && (sDst[lane] != sDst[lane - 1]);
    const unsigned long long mask = __ballot(f);
    const bool fF = sFlag[0] != 0, fL = sFlag[1] != 0;
    bf16x4 v[16];
#pragma unroll
    for (int j = 0; j < 16; ++j) v[j] = *(const bf16x4*)&A2t[col][j * 4];
    float sum = 0.f;
    int s0 = 0;
#pragma unroll
    for (int r = 0; r < 64; ++r) {
      sum += (float)v[r >> 2][r & 3];
      if (r == 63 || ((mask >> (r + 1)) & 1ull)) {
        float* addr = agg + (size_t)sDst[r] * H + col;
        const bool shared = (s0 == 0 && fF) || (r == 63 && fL);
        if (shared) atomicAdd(addr, sum);
        else *addr = sum;
        sum = 0.f;
        s0 = r + 1;
      }
    }
  }
}

// ---------------------------------------------------------------------------
// Fused node update. LDS union Abuf/A2 -> 4 blocks/CU.
// ---------------------------------------------------------------------------
__global__ __launch_bounds__(256, 4) void node_kernel(
    __bf16* __restrict__ h, const float* __restrict__ agg,
    const int* __restrict__ nrole, const int* __restrict__ ncol,
    const float* __restrict__ roleE, const float* __restrict__ colE,
    const __bf16* __restrict__ n1p, const float* __restrict__ n1b,
    const __bf16* __restrict__ n2p, const float* __restrict__ n2b,
    const float* __restrict__ lng, const float* __restrict__ lnb)
{
  __shared__ __align__(16) char uni[33792];
  __shared__ __bf16 sRole[8][8], sCol[3][8];
  __shared__ float sSum[64][4], sSsq[64][4];

  auto Abuf = (__bf16 (*)[72])uni;   // [64][72]
  auto A2   = (__bf16 (*)[264])uni;  // [64][264]

  const int tid  = threadIdx.x;
  const int lane = tid & 63;
  const int wave = tid >> 6;
  const int l15  = lane & 15;
  const int quad = lane >> 4;
  const int n0   = blockIdx.x * 64;
  const int colW = wave * 64;

  if (tid < 64) ((__bf16*)sRole)[tid] = (__bf16)roleE[tid];
  else if (tid < 88) ((__bf16*)sCol)[tid - 64] = (__bf16)colE[tid - 64];
  __syncthreads();

  f32x4 acc[4][4] = {};
  for (int s = 0; s < 9; ++s) {
    if (s) __syncthreads();
    if (s < 4) {
#pragma unroll
      for (int it = 0; it < 2; ++it) {
        const int t = tid + it * 256;
        const int row = t >> 3, seg = t & 7;
        const int n = n0 + row;
        bf16x8 v = bzero8();
        if (n < NN) v = *(const bf16x8*)(h + (size_t)n * H + s * 64 + seg * 8);
        *(bf16x8*)&Abuf[row][seg * 8] = v;
      }
    } else if (s < 8) {
#pragma unroll
      for (int it = 0; it < 2; ++it) {
        const int t = tid + it * 256;
        const int row = t >> 3, seg = t & 7;
        const int n = n0 + row;
        bf16x8 v = bzero8();
        if (n < NN) {
          const float* p = agg + (size_t)n * H + (s - 4) * 64 + seg * 8;
          const float4 u0 = *(const float4*)p;
          const float4 u1 = *(const float4*)(p + 4);
          v[0] = (__bf16)u0.x; v[1] = (__bf16)u0.y; v[2] = (__bf16)u0.z; v[3] = (__bf16)u0.w;
          v[4] = (__bf16)u1.x; v[5] = (__bf16)u1.y; v[6] = (__bf16)u1.z; v[7] = (__bf16)u1.w;
        }
        *(bf16x8*)&Abuf[row][seg * 8] = v;
      }
    } else {
      const int row = tid >> 2, q = tid & 3;
      const int n = n0 + row;
      __bf16* dp = &Abuf[row][q * 16];
      if (q == 0 && n < NN) {
        const int r = nrole[n], c = ncol[n];
#pragma unroll
        for (int j = 0; j < 8; ++j) { dp[j] = sRole[r][j]; dp[8 + j] = sCol[c][j]; }
      } else {
#pragma unroll
        for (int j = 0; j < 16; ++j) dp[j] = (__bf16)0.f;
      }
    }
    __syncthreads();
#pragma unroll
    for (int cc = 0; cc < 2; ++cc) {
      const int c = 2 * s + cc;
      if (c >= 17) break;
      bf16x8 bfr[4], afr[4];
#pragma unroll
      for (int nj = 0; nj < 4; ++nj)
        bfr[nj] = *(const bf16x8*)(n1p + ((size_t)c * 256 + colW + nj * 16 + l15) * 32 + quad * 8);
#pragma unroll
      for (int mi = 0; mi < 4; ++mi)
        afr[mi] = *(const bf16x8*)&Abuf[mi * 16 + l15][cc * 32 + quad * 8];
#pragma unroll
      for (int mi = 0; mi < 4; ++mi)
#pragma unroll
        for (int nj = 0; nj < 4; ++nj)
          acc[mi][nj] = mfma16(afr[mi], bfr[nj], acc[mi][nj]);
    }
  }
  __syncthreads();   // Abuf reads done before A2 (aliased) write

  float b1[4];
#pragma unroll
  for (int nj = 0; nj < 4; ++nj) b1[nj] = n1b[colW + nj * 16 + l15];
#pragma unroll
  for (int mi = 0; mi < 4; ++mi)
#pragma unroll
    for (int nj = 0; nj < 4; ++nj)
#pragma unroll
      for (int r = 0; r < 4; ++r)
        A2[mi * 16 + quad * 4 + r][colW + nj * 16 + l15] =
            (__bf16)silu_f(acc[mi][nj][r] + b1[nj]);
  __syncthreads();

  f32x4 acc2[4][4] = {};
#pragma unroll
  for (int c = 0; c < 8; ++c) {
    bf16x8 bfr[4], afr[4];
#pragma unroll
    for (int nj = 0; nj < 4; ++nj)
      bfr[nj] = *(const bf16x8*)(n2p + ((size_t)c * 256 + colW + nj * 16 + l15) * 32 + quad * 8);
#pragma unroll
    for (int mi = 0; mi < 4; ++mi)
      afr[mi] = *(const bf16x8*)&A2[mi * 16 + l15][c * 32 + quad * 8];
#pragma unroll
    for (int mi = 0; mi < 4; ++mi)
#pragma unroll
      for (int nj = 0; nj < 4; ++nj)
        acc2[mi][nj] = mfma16(afr[mi], bfr[nj], acc2[mi][nj]);
  }

  float b2[4], g4[4], bb4[4];
#pragma unroll
  for (int nj = 0; nj < 4; ++nj) {
    const int col = colW + nj * 16 + l15;
    b2[nj] = n2b[col]; g4[nj] = lng[col]; bb4[nj] = lnb[col];
  }
#pragma unroll
  for (int mi = 0; mi < 4; ++mi)
#pragma unroll
    for (int r = 0; r < 4; ++r) {
      const int n = n0 + mi * 16 + quad * 4 + r;
#pragma unroll
      for (int nj = 0; nj < 4; ++nj) {
        const float hv = (n < NN) ? (float)h[(size_t)n * H + colW + nj * 16 + l15] : 0.f;
        acc2[mi][nj][r] += b2[nj] + hv;
      }
    }
#pragma unroll
  for (int mi = 0; mi < 4; ++mi)
#pragma unroll
    for (int r = 0; r < 4; ++r) {
      float s1 = 0.f, s2 = 0.f;
#pragma unroll
      for (int nj = 0; nj < 4; ++nj) {
        const float v = acc2[mi][nj][r];
        s1 += v; s2 += v * v;
      }
#pragma unroll
      for (int d = 1; d < 16; d <<= 1) {
        s1 += __shfl_xor(s1, d, 16);
        s2 += __shfl_xor(s2, d, 16);
      }
      if (l15 == 0) {
        const int row = mi * 16 + quad * 4 + r;
        sSum[row][wave] = s1; sSsq[row][wave] = s2;
      }
    }
  __syncthreads();
#pragma unroll
  for (int mi = 0; mi < 4; ++mi)
#pragma unroll
    for (int r = 0; r < 4; ++r) {
      const int row = mi * 16 + quad * 4 + r;
      const int n = n0 + row;
      const float t1 = sSum[row][0] + sSum[row][1] + sSum[row][2] + sSum[row][3];
      const float t2 = sSsq[row][0] + sSsq[row][1] + sSsq[row][2] + sSsq[row][3];
      const float mu = t1 * (1.f / 256.f);
      float var = t2 * (1.f / 256.f) - mu * mu;
      var = var < 0.f ? 0.f : var;
      const float rstd = rsqrtf(var + 1e-5f);
      if (n < NN) {
#pragma unroll
        for (int nj = 0; nj < 4; ++nj) {
          const float o = g4[nj] * (acc2[mi][nj][r] - mu) * rstd + bb4[nj];
          h[(size_t)n * H + colW + nj * 16 + l15] = (__bf16)o;
        }
      }
    }
}

// ---------------------------------------------------------------------------
// Output projection.
// ---------------------------------------------------------------------------
__global__ __launch_bounds__(256) void out_kernel(
    const __bf16* __restrict__ h, const __bf16* __restrict__ outp,
    const float* __restrict__ outb, float* __restrict__ out)
{
  const int tid  = threadIdx.x;
  const int lane = tid & 63;
  const int wave = tid >> 6;
  const int l15  = lane & 15;
  const int quad = lane >> 4;
  const int m0   = blockIdx.x * 64 + wave * 16;
  int ar = m0 + l15;
  if (ar >= NN) ar = NN - 1;
  f32x4 acc[4] = {};
#pragma unroll
  for (int c = 0; c < 8; ++c) {
    const bf16x8 a = *(const bf16x8*)(h + (size_t)ar * H + c * 32 + quad * 8);
#pragma unroll
    for (int nj = 0; nj < 4; ++nj) {
      const bf16x8 b = *(const bf16x8*)(outp + ((size_t)c * 64 + nj * 16 + l15) * 32 + quad * 8);
      acc[nj] = mfma16(a, b, acc[nj]);
    }
  }
#pragma unroll
  for (int nj = 0; nj < 4; ++nj) {
    const float bb = outb[nj * 16 + l15];
#pragma unroll
    for (int r = 0; r < 4; ++r) {
      const int row = m0 + quad * 4 + r;
      if (row < NN) out[(size_t)row * 64 + nj * 16 + l15] = acc[nj][r] + bb;
    }
  }
}

// ---------------------------------------------------------------------------
extern "C" void kernel_launch(void* const* d_in, const int* in_sizes, int n_in,
                              void* d_out, int out_size, void* d_ws, size_t ws_size,
                              hipStream_t stream) {
  const float* scalars   = (const float*)d_in[0];
  const int*   ei        = (const int*)d_in[1];
  const int*   erel      = (const int*)d_in[2];
  const int*   ncol      = (const int*)d_in[3];
  const int*   nrole     = (const int*)d_in[4];
  const float* blk_role  = (const float*)d_in[5];
  const float* blk_col   = (const float*)d_in[6];
  const float* inw       = (const float*)d_in[7];
  const float* inb       = (const float*)d_in[8];
  const float* rel_embs  = (const float*)d_in[9];
  const float* role_embs = (const float*)d_in[10];
  const float* col_embs  = (const float*)d_in[11];
  const float* e1w       = (const float*)d_in[12];
  const float* e1b       = (const float*)d_in[13];
  const float* e2w       = (const float*)d_in[14];
  const float* e2b       = (const float*)d_in[15];
  const float* n1w       = (const float*)d_in[16];
  const float* n1b       = (const float*)d_in[17];
  const float* n2w       = (const float*)d_in[18];
  const float* n2b       = (const float*)d_in[19];
  const float* lng       = (const float*)d_in[20];
  const float* lnb       = (const float*)d_in[21];
  const float* outw      = (const float*)d_in[22];
  const float* outb      = (const float*)d_in[23];

  const int* srcI = ei;
  const int* dstI = ei + NE;

  char* ws = (char*)d_ws;
  size_t off = 0;
  auto take = [&](size_t bytes) -> char* {
    off = (off + 255) & ~(size_t)255;
    char* p = ws + off;
    off += bytes;
    return p;
  };
  __bf16* h    = (__bf16*)take((size_t)NN * H * 2);
  float*  agg  = (float*)take((size_t)NN * H * 4);
  __bf16* PS   = (__bf16*)take((size_t)NN * H * 2);
  __bf16* PD   = (__bf16*)take((size_t)NN * H * 2);
  __bf16* wsd  = (__bf16*)take((size_t)3 * 131072 * 2);
  __bf16* e2p  = (__bf16*)take((size_t)3 * 8 * 8192 * 2);
  __bf16* n1p  = (__bf16*)take((size_t)3 * 17 * 8192 * 2);
  __bf16* n2p  = (__bf16*)take((size_t)3 * 8 * 8192 * 2);
  __bf16* outp = (__bf16*)take((size_t)8 * 2048 * 2);
  float*  TR   = (float*)take((size_t)3 * 8 * 256 * 4);
  float*  TS   = (float*)take((size_t)3 * 24 * 256 * 4);
  float*  TD   = (float*)take((size_t)3 * 24 * 256 * 4);
  int*    cnt  = (int*)take((size_t)NBINS * 4);
  int*    srcS = (int*)take((size_t)NE * 4);
  int*    dstS = (int*)take((size_t)NE * 4);
  int*    relS = (int*)take((size_t)NE * 4);

  prep_kernel<<<4768, 256, 0, stream>>>(e1w, e2w, n1w, n2w, outw,
                                        wsd, e2p, n1p, n2p, outp);
  tbl_kernel<<<3, 256, 0, stream>>>(e1w, e1b, rel_embs, role_embs, col_embs,
                                    TR, TS, TD);
  embed_kernel<<<(NN + 15) / 16, 256, 0, stream>>>(scalars, ncol, nrole,
                                                   blk_col, blk_role, inw, inb, h);
  // counting sort of edges by dst
  hipMemsetAsync(cnt, 0, (size_t)NBINS * 4, stream);
  hist_kernel<<<(NE + 255) / 256, 256, 0, stream>>>(dstI, cnt);
  scan_kernel<<<1, 256, 0, stream>>>(cnt);
  scatter_kernel<<<(NE + 255) / 256, 256, 0, stream>>>(srcI, dstI, erel, cnt,
                                                       srcS, dstS, relS);

  for (int l = 0; l < 3; ++l) {
    hipMemsetAsync(agg, 0, (size_t)NN * H * 4, stream);
    pre_kernel<<<2 * ((NN + 63) / 64), 256, 0, stream>>>(
        h, nrole, ncol, wsd + (size_t)l * 131072,
        TS + (size_t)l * 24 * 256, TD + (size_t)l * 24 * 256, PS, PD);
    edge_kernel<<<NE / 64, 256, 0, stream>>>(
        PS, PD, agg, srcS, dstS, relS, TR + (size_t)l * 8 * 256,
        e2p + (size_t)l * 8 * 8192, e2b + (size_t)l * 256);
    node_kernel<<<(NN + 63) / 64, 256, 0, stream>>>(
        h, agg, nrole, ncol,
        role_embs + (size_t)l * 64, col_embs + (size_t)l * 24,
        n1p + (size_t)l * 17 * 8192, n1b + (size_t)l * 256,
        n2p + (size_t)l * 8 * 8192,  n2b + (size_t)l * 256,
        lng + (size_t)l * 256, lnb + (size_t)l * 256);
  }
  out_kernel<<<(NN + 63) / 64, 256, 0, stream>>>(h, outp, outb, (float*)d_out);
}